// Round 2
// baseline (1409.339 us; speedup 1.0000x reference)
//
#include <hip/hip_runtime.h>

#define DEVI __device__ __forceinline__

static constexpr int Bb = 64;
static constexpr int Ss = 3000;
static constexpr int Mm = Bb * Ss;      // 192000
static constexpr int NCH = 12;          // sequence chunks (scans)
static constexpr int CLEN = 250;        // chunk length (scans)
static constexpr int WARM = 64;         // scan warmup steps
static constexpr int RCH = 60;          // rnn chunks
static constexpr int RCLEN = 50;        // rnn chunk length
static constexpr int RWARM = 32;        // rnn warmup steps

DEVI float fast_tanh(float x) {
    float e = __expf(2.0f * x);
    return 1.0f - 2.0f / (e + 1.0f);
}
DEVI float fast_sigmoid(float x) {
    return 1.0f / (1.0f + __expf(-x));
}

// ---------------- RNN (hidden=4): LDS-staged x, 60 chunks/batch ----------------
__global__ __launch_bounds__(64) void rnn_kernel2(const float* __restrict__ x,
                                                  const float* __restrict__ wih,
                                                  const float* __restrict__ whh,
                                                  const float* __restrict__ bih,
                                                  const float* __restrict__ bhh,
                                                  float* __restrict__ hout) {
    __shared__ float xs[Ss];
    int b = blockIdx.x;
    for (int i = threadIdx.x; i < Ss / 4; i += 64) {
        *(float4*)&xs[i * 4] = *(const float4*)&x[b * Ss + i * 4];
    }
    __syncthreads();
    int ck = threadIdx.x;
    if (ck >= RCH) return;
    float w[4][4], wi[4], bc[4];
#pragma unroll
    for (int j = 0; j < 4; ++j) {
        wi[j] = wih[j];
        bc[j] = bih[j] + bhh[j];
#pragma unroll
        for (int i = 0; i < 4; ++i) w[j][i] = whh[j * 4 + i];
    }
    float h0 = 0.f, h1 = 0.f, h2 = 0.f, h3 = 0.f;
    int sc = ck * RCLEN;
    int sb = ck ? (sc - RWARM) : 0;
#pragma unroll 4
    for (int s = sb; s < sc; ++s) {
        float xv = xs[s];
        float n0 = fast_tanh(fmaf(xv, wi[0], bc[0]) + w[0][0]*h0 + w[0][1]*h1 + w[0][2]*h2 + w[0][3]*h3);
        float n1 = fast_tanh(fmaf(xv, wi[1], bc[1]) + w[1][0]*h0 + w[1][1]*h1 + w[1][2]*h2 + w[1][3]*h3);
        float n2 = fast_tanh(fmaf(xv, wi[2], bc[2]) + w[2][0]*h0 + w[2][1]*h1 + w[2][2]*h2 + w[2][3]*h3);
        float n3 = fast_tanh(fmaf(xv, wi[3], bc[3]) + w[3][0]*h0 + w[3][1]*h1 + w[3][2]*h2 + w[3][3]*h3);
        h0 = n0; h1 = n1; h2 = n2; h3 = n3;
    }
#pragma unroll 5
    for (int s = sc; s < sc + RCLEN; ++s) {
        float xv = xs[s];
        float n0 = fast_tanh(fmaf(xv, wi[0], bc[0]) + w[0][0]*h0 + w[0][1]*h1 + w[0][2]*h2 + w[0][3]*h3);
        float n1 = fast_tanh(fmaf(xv, wi[1], bc[1]) + w[1][0]*h0 + w[1][1]*h1 + w[1][2]*h2 + w[1][3]*h3);
        float n2 = fast_tanh(fmaf(xv, wi[2], bc[2]) + w[2][0]*h0 + w[2][1]*h1 + w[2][2]*h2 + w[2][3]*h3);
        float n3 = fast_tanh(fmaf(xv, wi[3], bc[3]) + w[3][0]*h0 + w[3][1]*h1 + w[3][2]*h2 + w[3][3]*h3);
        h0 = n0; h1 = n1; h2 = n2; h3 = n3;
        *(float4*)&hout[(size_t)(b * Ss + s) * 4] = make_float4(h0, h1, h2, h3);
    }
}

// ---------------- big QRNN GEMM: 128x128 tile, 8x8 micro ----------------
// A: (M,K) row-major (lda=K).  ZF compact (M, Wout): cols [0,Hg)=tanh(z), [Hg,2Hg)=sigmoid(f).
template <int K>
__global__ __launch_bounds__(256) void qrnn_gemm_big(const float* __restrict__ A,
                                                     const float* __restrict__ W,
                                                     const float* __restrict__ bias,
                                                     float* __restrict__ ZF,
                                                     int Nfull, int Wout, int Hg, int z0, int f0) {
    constexpr int BK = (K < 32) ? K : 32;
    __shared__ float As[BK][132];
    __shared__ float Bs[BK][128];
    const int tid = threadIdx.x;
    const int tx = tid & 15, ty = tid >> 4;
    const int n0 = blockIdx.x * 128;   // N-block fastest -> A panel L2 reuse
    const int m0 = blockIdx.y * 128;
    float acc[8][8] = {};

    for (int k0 = 0; k0 < K; k0 += BK) {
        constexpr int KQ = BK / 4;
        for (int v = tid; v < 128 * KQ; v += 256) {
            int m = v / KQ, kq = v % KQ;
            float4 av = *(const float4*)&A[(size_t)(m0 + m) * K + k0 + kq * 4];
            As[kq * 4 + 0][m] = av.x;
            As[kq * 4 + 1][m] = av.y;
            As[kq * 4 + 2][m] = av.z;
            As[kq * 4 + 3][m] = av.w;
        }
        for (int v = tid; v < BK * 32; v += 256) {
            int ki = v >> 5, nq = v & 31;
            int j = nq * 4;
            int gj = n0 + j;
            int wc = (gj < Hg) ? (z0 + gj) : (f0 + (gj - Hg));
            float4 bv = *(const float4*)&W[(size_t)(k0 + ki) * Nfull + wc];
            *(float4*)&Bs[ki][j] = bv;
        }
        __syncthreads();
#pragma unroll
        for (int kk = 0; kk < BK; ++kk) {
            float4 a0 = *(const float4*)&As[kk][ty * 4];
            float4 a1 = *(const float4*)&As[kk][64 + ty * 4];
            float4 b0 = *(const float4*)&Bs[kk][tx * 4];
            float4 b1 = *(const float4*)&Bs[kk][64 + tx * 4];
            float av[8] = {a0.x, a0.y, a0.z, a0.w, a1.x, a1.y, a1.z, a1.w};
            float bv[8] = {b0.x, b0.y, b0.z, b0.w, b1.x, b1.y, b1.z, b1.w};
#pragma unroll
            for (int i = 0; i < 8; ++i)
#pragma unroll
                for (int j = 0; j < 8; ++j) acc[i][j] = fmaf(av[i], bv[j], acc[i][j]);
        }
        __syncthreads();
    }
#pragma unroll
    for (int jh = 0; jh < 2; ++jh) {
        int jl = jh * 64 + tx * 4;
        int gj = n0 + jl;
        bool isz = gj < Hg;
        int wc = isz ? (z0 + gj) : (f0 + (gj - Hg));
        float4 b4 = *(const float4*)&bias[wc];
        float bb[4] = {b4.x, b4.y, b4.z, b4.w};
#pragma unroll
        for (int ih = 0; ih < 2; ++ih) {
#pragma unroll
            for (int i = 0; i < 4; ++i) {
                int gm = m0 + ih * 64 + ty * 4 + i;
                float o[4];
#pragma unroll
                for (int jj = 0; jj < 4; ++jj) {
                    float v = acc[ih * 4 + i][jh * 4 + jj] + bb[jj];
                    o[jj] = isz ? fast_tanh(v) : fast_sigmoid(v);
                }
                *(float4*)&ZF[(size_t)gm * Wout + gj] = make_float4(o[0], o[1], o[2], o[3]);
            }
        }
    }
}

// ---------------- small QRNN GEMM (64x64) for tiny layers / fallback ----------------
template <int K>
__global__ __launch_bounds__(256) void qrnn_gemm(const float* __restrict__ A,
                                                 const float* __restrict__ W,
                                                 const float* __restrict__ bias,
                                                 float* __restrict__ ZF,
                                                 int Nfull, int Wout, int Hg, int z0, int f0) {
    constexpr int BM = 64, BN = 64;
    constexpr int BK = (K < 32) ? K : 32;
    __shared__ float As[BK][BM + 4];
    __shared__ float Bs[BK][BN];
    const int tid = threadIdx.x;
    const int tx = tid % 16, ty = tid / 16;
    const int m0 = blockIdx.x * BM;
    const int n0 = blockIdx.y * BN;
    float acc[4][4] = {};

    for (int k0 = 0; k0 < K; k0 += BK) {
        constexpr int KQ = BK / 4;
        constexpr int AV = BM * KQ;
        for (int v = tid; v < AV; v += 256) {
            int m = v / KQ, kq = v % KQ;
            float4 av = *(const float4*)&A[(size_t)(m0 + m) * K + k0 + kq * 4];
            As[kq * 4 + 0][m] = av.x;
            As[kq * 4 + 1][m] = av.y;
            As[kq * 4 + 2][m] = av.z;
            As[kq * 4 + 3][m] = av.w;
        }
        constexpr int BV = BK * 16;
        for (int v = tid; v < BV; v += 256) {
            int ki = v / 16, nq = v % 16;
            int j = n0 + nq * 4;
            float4 bv = make_float4(0.f, 0.f, 0.f, 0.f);
            if (j < Wout) {
                int wc = (j < Hg) ? (z0 + j) : (f0 + (j - Hg));
                bv = *(const float4*)&W[(size_t)(k0 + ki) * Nfull + wc];
            }
            *(float4*)&Bs[ki][nq * 4] = bv;
        }
        __syncthreads();
#pragma unroll
        for (int kk = 0; kk < BK; ++kk) {
            float a[4];
#pragma unroll
            for (int i = 0; i < 4; ++i) a[i] = As[kk][ty * 4 + i];
            float4 bv = *(const float4*)&Bs[kk][tx * 4];
            float bb[4] = {bv.x, bv.y, bv.z, bv.w};
#pragma unroll
            for (int i = 0; i < 4; ++i)
#pragma unroll
                for (int j = 0; j < 4; ++j) acc[i][j] = fmaf(a[i], bb[j], acc[i][j]);
        }
        __syncthreads();
    }
    int jb = n0 + tx * 4;
    if (jb < Wout) {
        bool isz = jb < Hg;
#pragma unroll
        for (int i = 0; i < 4; ++i) {
            int gm = m0 + ty * 4 + i;
            float o[4];
#pragma unroll
            for (int jj = 0; jj < 4; ++jj) {
                int j = jb + jj;
                int wc = isz ? (z0 + j) : (f0 + (j - Hg));
                float v = acc[i][jj] + bias[wc];
                o[jj] = isz ? fast_tanh(v) : fast_sigmoid(v);
            }
            *(float4*)&ZF[(size_t)gm * Wout + jb] = make_float4(o[0], o[1], o[2], o[3]);
        }
    }
}

// ---------------- fo-pool scan (layers 1-4), chunked with warmup ----------------
__global__ void scan_kernel(const float* __restrict__ zf, float* __restrict__ hout,
                            int Hg, int W2, int Hfull, int ch0) {
    int id = blockIdx.x * blockDim.x + threadIdx.x;
    int total = Bb * NCH * Hg;
    if (id >= total) return;
    int c = id % Hg;
    int p = id / Hg;
    int b = p / NCH, ck = p % NCH;
    int sc = ck * CLEN;
    float h = 0.f;
    if (ck) {
#pragma unroll 4
        for (int s = sc - WARM; s < sc; ++s) {
            size_t base = (size_t)(b * Ss + s) * W2;
            float z = zf[base + c], f = zf[base + Hg + c];
            h = fmaf(f, h - z, z);
        }
    }
#pragma unroll 5
    for (int s = sc; s < sc + CLEN; ++s) {
        size_t base = (size_t)(b * Ss + s) * W2;
        float z = zf[base + c], f = zf[base + Hg + c];
        h = fmaf(f, h - z, z);
        hout[(size_t)(b * Ss + s) * Hfull + ch0 + c] = h;
    }
}

// ---------------- L5 scan fused with mean-pool over channels ----------------
template <int HG>
__global__ void scan_pool_kernel(const float* __restrict__ zf, float* __restrict__ pooled,
                                 int initflag) {
    constexpr int W2 = 2 * HG;
    constexpr int WIN = 50;
    __shared__ float tile[WIN][HG + 1];
    int b = blockIdx.x, ck = blockIdx.y;
    int c = threadIdx.x;
    int sc = ck * CLEN;
    float h = 0.f;
    if (ck) {
#pragma unroll 4
        for (int s = sc - WARM; s < sc; ++s) {
            size_t base = (size_t)(b * Ss + s) * W2;
            float z = zf[base + c], f = zf[base + HG + c];
            h = fmaf(f, h - z, z);
        }
    }
    for (int w0 = 0; w0 < CLEN; w0 += WIN) {
#pragma unroll 5
        for (int r = 0; r < WIN; ++r) {
            size_t base = (size_t)(b * Ss + sc + w0 + r) * W2;
            float z = zf[base + c], f = zf[base + HG + c];
            h = fmaf(f, h - z, z);
            tile[r][c] = h;
        }
        __syncthreads();
#pragma unroll
        for (int stride = HG >> 1; stride >= 1; stride >>= 1) {
            for (int idx = c; idx < WIN * stride; idx += HG) {
                int r = idx / stride, cc = idx % stride;
                tile[r][cc] += tile[r][cc + stride];
            }
            __syncthreads();
        }
        if (c < WIN) {
            size_t po = (size_t)b * Ss + sc + w0 + c;
            float v = tile[c][0] * (1.f / 256.f);
            if (initflag) pooled[po] = v;
            else pooled[po] += v;
        }
        __syncthreads();
    }
}

// ---------------- MLP ----------------
__global__ __launch_bounds__(256) void mlp1_kernel(const float* __restrict__ xp,
                                                   const float* __restrict__ w1,
                                                   float* __restrict__ parts) {
    const int n0 = blockIdx.x * 64;
    const int ks = blockIdx.y;
    const int kbeg = ks * 250;
    const int nl = threadIdx.x % 64, mg = threadIdx.x / 64;
    __shared__ float xs[50][68];
    float acc[16] = {};
    for (int kc = 0; kc < 5; ++kc) {
        int k0 = kbeg + kc * 50;
        __syncthreads();
        for (int idx = threadIdx.x; idx < 64 * 50; idx += 256) {
            int r = idx / 50, cc = idx % 50;
            xs[cc][r] = xp[r * Ss + k0 + cc];
        }
        __syncthreads();
#pragma unroll 5
        for (int kk = 0; kk < 50; ++kk) {
            float wv = w1[(size_t)(k0 + kk) * 1024 + n0 + nl];
#pragma unroll
            for (int q = 0; q < 4; ++q) {
                float4 xv = *(const float4*)&xs[kk][mg * 16 + q * 4];
                acc[q * 4 + 0] = fmaf(xv.x, wv, acc[q * 4 + 0]);
                acc[q * 4 + 1] = fmaf(xv.y, wv, acc[q * 4 + 1]);
                acc[q * 4 + 2] = fmaf(xv.z, wv, acc[q * 4 + 2]);
                acc[q * 4 + 3] = fmaf(xv.w, wv, acc[q * 4 + 3]);
            }
        }
    }
#pragma unroll
    for (int i = 0; i < 16; ++i) {
        int m = mg * 16 + i;
        parts[((size_t)ks * 64 + m) * 1024 + n0 + nl] = acc[i];
    }
}

__global__ void mlp1_reduce(const float* __restrict__ parts, const float* __restrict__ b1,
                            float* __restrict__ h1) {
    int id = blockIdx.x * 256 + threadIdx.x;
    int n = id % 1024, m = id / 1024;
    float s = b1[n];
#pragma unroll
    for (int ks = 0; ks < 12; ++ks) s += parts[((size_t)ks * 64 + m) * 1024 + n];
    h1[id] = fmaxf(s, 0.f);
}

__global__ void mlp2_kernel(const float* __restrict__ h1, const float* __restrict__ w2,
                            const float* __restrict__ b2, float* __restrict__ h2) {
    int m = blockIdx.x, n = threadIdx.x;
    float acc = 0.f;
#pragma unroll 8
    for (int k = 0; k < 1024; ++k) acc = fmaf(h1[m * 1024 + k], w2[k * 128 + n], acc);
    h2[m * 128 + n] = fmaxf(acc + b2[n], 0.f);
}

__global__ void mlp3_kernel(const float* __restrict__ h2, const float* __restrict__ w3,
                            const float* __restrict__ b3, float* __restrict__ out) {
    int t = threadIdx.x;
    if (t >= 640) return;
    int m = t / 10, n = t % 10;
    float acc = 0.f;
#pragma unroll
    for (int k = 0; k < 128; ++k) acc = fmaf(h2[m * 128 + k], w3[k * 10 + n], acc);
    out[t] = fmaxf(acc + b3[n], 0.f);
}

// ---------------- launcher ----------------
extern "C" void kernel_launch(void* const* d_in, const int* in_sizes, int n_in,
                              void* d_out, int out_size, void* d_ws, size_t ws_size,
                              hipStream_t stream) {
    const float* x   = (const float*)d_in[0];
    const float* wih = (const float*)d_in[1];
    const float* whh = (const float*)d_in[2];
    const float* bih = (const float*)d_in[3];
    const float* bhh = (const float*)d_in[4];
    const float* qw[5] = {(const float*)d_in[5], (const float*)d_in[7], (const float*)d_in[9],
                          (const float*)d_in[11], (const float*)d_in[13]};
    const float* qb[5] = {(const float*)d_in[6], (const float*)d_in[8], (const float*)d_in[10],
                          (const float*)d_in[12], (const float*)d_in[14]};
    const float* w1 = (const float*)d_in[15];
    const float* b1 = (const float*)d_in[16];
    const float* w2 = (const float*)d_in[17];
    const float* b2 = (const float*)d_in[18];
    const float* w3 = (const float*)d_in[19];
    const float* b3 = (const float*)d_in[20];
    float* out = (float*)d_out;

    const size_t hA_sz = (size_t)Mm * 128 * 4;
    const size_t hB_sz = (size_t)Mm * 64 * 4;
    const size_t pooled_sz = (size_t)Bb * Ss * 4;
    const size_t parts_sz = 12ull * 64 * 1024 * 4;
    const size_t h1_sz = 64ull * 1024 * 4;
    const size_t h2_sz = 64ull * 128 * 4;
    const size_t tail = pooled_sz + parts_sz + h1_sz + h2_sz;

    int G[5] = {1, 1, 1, 1, 2};
    size_t zf_sz = (size_t)Mm * 256 * 4;
    if (ws_size < hA_sz + hB_sz + zf_sz + tail) {
        G[3] = 2; G[4] = 4; zf_sz = (size_t)Mm * 128 * 4;
    }
    if (ws_size < hA_sz + hB_sz + zf_sz + tail) {
        G[2] = 2; G[3] = 4; G[4] = 8; zf_sz = (size_t)Mm * 64 * 4;
    }

    char* ws = (char*)d_ws;
    float* hA = (float*)ws;
    float* hB = (float*)(ws + hA_sz);
    float* zfb = (float*)(ws + hA_sz + hB_sz);
    float* pooled = (float*)(ws + hA_sz + hB_sz + zf_sz);
    float* parts = (float*)(ws + hA_sz + hB_sz + zf_sz + pooled_sz);
    float* h1m = (float*)(ws + hA_sz + hB_sz + zf_sz + pooled_sz + parts_sz);
    float* h2m = (float*)(ws + hA_sz + hB_sz + zf_sz + pooled_sz + parts_sz + h1_sz);

    rnn_kernel2<<<Bb, 64, 0, stream>>>(x, wih, whh, bih, bhh, hA);

    const int Hs[5] = {16, 32, 64, 128, 256};
    const int Ks[5] = {4, 16, 32, 64, 128};
    float* hcur = hA;
    float* hnext = hB;
    for (int L = 0; L < 5; ++L) {
        int H = Hs[L], K = Ks[L], g = G[L], Hg = H / g, Wout = 2 * Hg, Nfull = 2 * H;
        bool big = (Wout % 128 == 0) && (K >= 32);
        for (int gi = 0; gi < g; ++gi) {
            int z0 = gi * Hg, f0 = H + gi * Hg;
            if (big) {
                dim3 grid(Wout / 128, Mm / 128);
                switch (K) {
                    case 32:  qrnn_gemm_big<32><<<grid, 256, 0, stream>>>(hcur, qw[L], qb[L], zfb, Nfull, Wout, Hg, z0, f0); break;
                    case 64:  qrnn_gemm_big<64><<<grid, 256, 0, stream>>>(hcur, qw[L], qb[L], zfb, Nfull, Wout, Hg, z0, f0); break;
                    default:  qrnn_gemm_big<128><<<grid, 256, 0, stream>>>(hcur, qw[L], qb[L], zfb, Nfull, Wout, Hg, z0, f0); break;
                }
            } else {
                dim3 grid(Mm / 64, (Wout + 63) / 64);
                switch (K) {
                    case 4:   qrnn_gemm<4><<<grid, 256, 0, stream>>>(hcur, qw[L], qb[L], zfb, Nfull, Wout, Hg, z0, f0); break;
                    case 16:  qrnn_gemm<16><<<grid, 256, 0, stream>>>(hcur, qw[L], qb[L], zfb, Nfull, Wout, Hg, z0, f0); break;
                    case 32:  qrnn_gemm<32><<<grid, 256, 0, stream>>>(hcur, qw[L], qb[L], zfb, Nfull, Wout, Hg, z0, f0); break;
                    case 64:  qrnn_gemm<64><<<grid, 256, 0, stream>>>(hcur, qw[L], qb[L], zfb, Nfull, Wout, Hg, z0, f0); break;
                    default:  qrnn_gemm<128><<<grid, 256, 0, stream>>>(hcur, qw[L], qb[L], zfb, Nfull, Wout, Hg, z0, f0); break;
                }
            }
            if (L < 4) {
                int total = Bb * NCH * Hg;
                scan_kernel<<<(total + 255) / 256, 256, 0, stream>>>(zfb, hnext, Hg, Wout, H, z0);
            } else {
                dim3 g2(Bb, NCH);
                if (Hg == 128)      scan_pool_kernel<128><<<g2, 128, 0, stream>>>(zfb, pooled, gi == 0);
                else if (Hg == 64)  scan_pool_kernel<64><<<g2, 64, 0, stream>>>(zfb, pooled, gi == 0);
                else                scan_pool_kernel<32><<<g2, 32, 0, stream>>>(zfb, pooled, gi == 0);
            }
        }
        if (L < 4) { float* t = hcur; hcur = hnext; hnext = t; }
    }

    mlp1_kernel<<<dim3(16, 12), 256, 0, stream>>>(pooled, w1, parts);
    mlp1_reduce<<<256, 256, 0, stream>>>(parts, b1, h1m);
    mlp2_kernel<<<64, 128, 0, stream>>>(h1m, w2, b2, h2m);
    mlp3_kernel<<<1, 640, 0, stream>>>(h2m, w3, b3, out);
    (void)in_sizes; (void)n_in; (void)out_size;
}

// Round 3
// 1059.522 us; speedup vs baseline: 1.3302x; 1.3302x over previous
//
#include <hip/hip_runtime.h>

#define DEVI __device__ __forceinline__

static constexpr int Bb = 64;
static constexpr int Ss = 3000;
static constexpr int Mm = Bb * Ss;      // 192000
static constexpr int NCH = 12;          // sequence chunks (scans)
static constexpr int CLEN = 250;        // chunk length (scans)
static constexpr int WARM = 64;         // scan warmup steps
static constexpr int RCH = 60;          // rnn chunks
static constexpr int RCLEN = 50;        // rnn chunk length
static constexpr int RWARM = 32;        // rnn warmup steps

typedef short bs8 __attribute__((ext_vector_type(8)));
typedef short bs4 __attribute__((ext_vector_type(4)));
typedef float f32x4 __attribute__((ext_vector_type(4)));

DEVI float fast_tanh(float x) {
    float e = __expf(2.0f * x);
    return 1.0f - 2.0f / (e + 1.0f);
}
DEVI float fast_sigmoid(float x) {
    return 1.0f / (1.0f + __expf(-x));
}
DEVI unsigned short f2bf(float f) {
    unsigned u = __float_as_uint(f);
    u += 0x7FFF + ((u >> 16) & 1);
    return (unsigned short)(u >> 16);
}
DEVI float bf2f(unsigned short h) { return __uint_as_float(((unsigned)h) << 16); }

// ---------------- RNN (hidden=4): LDS-staged x, 60 chunks/batch ----------------
__global__ __launch_bounds__(64) void rnn_kernel2(const float* __restrict__ x,
                                                  const float* __restrict__ wih,
                                                  const float* __restrict__ whh,
                                                  const float* __restrict__ bih,
                                                  const float* __restrict__ bhh,
                                                  float* __restrict__ hout) {
    __shared__ float xs[Ss];
    int b = blockIdx.x;
    for (int i = threadIdx.x; i < Ss / 4; i += 64) {
        *(float4*)&xs[i * 4] = *(const float4*)&x[b * Ss + i * 4];
    }
    __syncthreads();
    int ck = threadIdx.x;
    if (ck >= RCH) return;
    float w[4][4], wi[4], bc[4];
#pragma unroll
    for (int j = 0; j < 4; ++j) {
        wi[j] = wih[j];
        bc[j] = bih[j] + bhh[j];
#pragma unroll
        for (int i = 0; i < 4; ++i) w[j][i] = whh[j * 4 + i];
    }
    float h0 = 0.f, h1 = 0.f, h2 = 0.f, h3 = 0.f;
    int sc = ck * RCLEN;
    int sb = ck ? (sc - RWARM) : 0;
#pragma unroll 4
    for (int s = sb; s < sc; ++s) {
        float xv = xs[s];
        float n0 = fast_tanh(fmaf(xv, wi[0], bc[0]) + w[0][0]*h0 + w[0][1]*h1 + w[0][2]*h2 + w[0][3]*h3);
        float n1 = fast_tanh(fmaf(xv, wi[1], bc[1]) + w[1][0]*h0 + w[1][1]*h1 + w[1][2]*h2 + w[1][3]*h3);
        float n2 = fast_tanh(fmaf(xv, wi[2], bc[2]) + w[2][0]*h0 + w[2][1]*h1 + w[2][2]*h2 + w[2][3]*h3);
        float n3 = fast_tanh(fmaf(xv, wi[3], bc[3]) + w[3][0]*h0 + w[3][1]*h1 + w[3][2]*h2 + w[3][3]*h3);
        h0 = n0; h1 = n1; h2 = n2; h3 = n3;
    }
#pragma unroll 5
    for (int s = sc; s < sc + RCLEN; ++s) {
        float xv = xs[s];
        float n0 = fast_tanh(fmaf(xv, wi[0], bc[0]) + w[0][0]*h0 + w[0][1]*h1 + w[0][2]*h2 + w[0][3]*h3);
        float n1 = fast_tanh(fmaf(xv, wi[1], bc[1]) + w[1][0]*h0 + w[1][1]*h1 + w[1][2]*h2 + w[1][3]*h3);
        float n2 = fast_tanh(fmaf(xv, wi[2], bc[2]) + w[2][0]*h0 + w[2][1]*h1 + w[2][2]*h2 + w[2][3]*h3);
        float n3 = fast_tanh(fmaf(xv, wi[3], bc[3]) + w[3][0]*h0 + w[3][1]*h1 + w[3][2]*h2 + w[3][3]*h3);
        h0 = n0; h1 = n1; h2 = n2; h3 = n3;
        *(float4*)&hout[(size_t)(b * Ss + s) * 4] = make_float4(h0, h1, h2, h3);
    }
}

// ---------------- MFMA QRNN GEMM: 128x128 tile, bf16 hi/lo split (3-term) ----------------
// A: (M,K) fp32 row-major.  ZF compact (M, Wout): cols [0,Hg)=tanh(z), [Hg,2Hg)=sigmoid(f).
// Fragment k-mapping is OUR choice (bijection argument): slot (g,j) -> k = s*32+g*8+j for both
// A and B fragments. C/D layout is the HW-verified one: col=lane&15, row=(lane>>4)*4+reg.
template <int K>
__global__ __launch_bounds__(256) void qrnn_gemm_mfma(const float* __restrict__ A,
                                                      const float* __restrict__ W,
                                                      const float* __restrict__ bias,
                                                      float* __restrict__ ZF,
                                                      int Nfull, int Wout, int Hg, int z0, int f0) {
    constexpr int BM = 128, BN = 128;
    constexpr int BK = (K < 64) ? K : 64;
    constexpr int NS = BK / 32;            // k-steps per chunk (1 or 2)
    constexpr int NCHK = K / BK;           // chunks
    constexpr int ASLOT = NS * 8 * 64;     // 16B fragment slots
    constexpr int BSLOT = NS * 8 * 64;
    __shared__ short Ah[ASLOT * 8];
    __shared__ short Al[ASLOT * 8];
    __shared__ short Bh[BSLOT * 8];
    __shared__ short Bl[BSLOT * 8];

    const int tid = threadIdx.x;
    const int lane = tid & 63;
    const int wid = tid >> 6;
    const int wr = wid >> 1, wcn = wid & 1;
    const int m0 = blockIdx.y * BM;
    const int n0 = blockIdx.x * BN;

    f32x4 acc[4][4] = {};

    for (int kc = 0; kc < NCHK; ++kc) {
        const int kb = kc * BK;
        if (kc) __syncthreads();
        // ---- stage A (coalesced float4 reads, scatter to fragment layout) ----
        constexpr int AQ = BM * BK / 4;
        for (int v = tid; v < AQ; v += 256) {
            int row = v / (BK / 4);
            int cq  = v % (BK / 4);
            const float4 a = *(const float4*)&A[(size_t)(m0 + row) * K + kb + cq * 4];
            int k = cq * 4;
            int s = k >> 5, g = (k >> 3) & 3, j = k & 7;   // j in {0,4}
            int slot = ((s * 8 + (row >> 4)) * 64 + ((g << 4) | (row & 15))) * 8 + j;
            float fx[4] = {a.x, a.y, a.z, a.w};
            bs4 hi, lo;
#pragma unroll
            for (int e = 0; e < 4; ++e) {
                unsigned short h = f2bf(fx[e]);
                hi[e] = (short)h;
                lo[e] = (short)f2bf(fx[e] - bf2f(h));
            }
            *(bs4*)&Ah[slot] = hi;
            *(bs4*)&Al[slot] = lo;
        }
        // ---- stage B (weights; small & L2-hot) ----
        for (int q = tid; q < BSLOT; q += 256) {
            int l = q & 63, fr = q >> 6;
            int s = fr >> 3, nb = fr & 7;
            int colg = n0 + nb * 16 + (l & 15);
            int wc = (colg < Hg) ? (z0 + colg) : (f0 + (colg - Hg));
            int kk = kb + s * 32 + (l >> 4) * 8;
            bs8 hi, lo;
#pragma unroll
            for (int j = 0; j < 8; ++j) {
                float wv = W[(size_t)(kk + j) * Nfull + wc];
                unsigned short h = f2bf(wv);
                hi[j] = (short)h;
                lo[j] = (short)f2bf(wv - bf2f(h));
            }
            *(bs8*)&Bh[q * 8] = hi;
            *(bs8*)&Bl[q * 8] = lo;
        }
        __syncthreads();
        // ---- MFMA compute: wave (wr,wcn) owns 64x64 = 4x4 frags of 16x16 ----
#pragma unroll
        for (int s = 0; s < NS; ++s) {
            bs8 ah[4], al[4], bh[4], bl[4];
#pragma unroll
            for (int i = 0; i < 4; ++i) {
                int fa = ((s * 8 + wr * 4 + i) * 64 + lane) * 8;
                ah[i] = *(const bs8*)&Ah[fa];
                al[i] = *(const bs8*)&Al[fa];
                int fb = ((s * 8 + wcn * 4 + i) * 64 + lane) * 8;
                bh[i] = *(const bs8*)&Bh[fb];
                bl[i] = *(const bs8*)&Bl[fb];
            }
#pragma unroll
            for (int i = 0; i < 4; ++i)
#pragma unroll
                for (int j = 0; j < 4; ++j) {
                    acc[i][j] = __builtin_amdgcn_mfma_f32_16x16x32_bf16(ah[i], bh[j], acc[i][j], 0, 0, 0);
                    acc[i][j] = __builtin_amdgcn_mfma_f32_16x16x32_bf16(al[i], bh[j], acc[i][j], 0, 0, 0);
                    acc[i][j] = __builtin_amdgcn_mfma_f32_16x16x32_bf16(ah[i], bl[j], acc[i][j], 0, 0, 0);
                }
        }
    }
    // ---- epilogue: bias + activation, store fp32 ----
#pragma unroll
    for (int j = 0; j < 4; ++j) {
        int colg = n0 + wcn * 64 + j * 16 + (lane & 15);
        bool isz = colg < Hg;
        int wc = isz ? (z0 + colg) : (f0 + (colg - Hg));
        float bv = bias[wc];
#pragma unroll
        for (int i = 0; i < 4; ++i) {
            int row = m0 + wr * 64 + i * 16 + (lane >> 4) * 4;
#pragma unroll
            for (int r = 0; r < 4; ++r) {
                float v = acc[i][j][r] + bv;
                v = isz ? fast_tanh(v) : fast_sigmoid(v);
                ZF[(size_t)(row + r) * Wout + colg] = v;
            }
        }
    }
}

// ---------------- small QRNN GEMM (64x64) for tiny layers / fallback ----------------
template <int K>
__global__ __launch_bounds__(256) void qrnn_gemm(const float* __restrict__ A,
                                                 const float* __restrict__ W,
                                                 const float* __restrict__ bias,
                                                 float* __restrict__ ZF,
                                                 int Nfull, int Wout, int Hg, int z0, int f0) {
    constexpr int BM = 64, BN = 64;
    constexpr int BK = (K < 32) ? K : 32;
    __shared__ float As[BK][BM + 4];
    __shared__ float Bs[BK][BN];
    const int tid = threadIdx.x;
    const int tx = tid % 16, ty = tid / 16;
    const int m0 = blockIdx.x * BM;
    const int n0 = blockIdx.y * BN;
    float acc[4][4] = {};

    for (int k0 = 0; k0 < K; k0 += BK) {
        constexpr int KQ = BK / 4;
        constexpr int AV = BM * KQ;
        for (int v = tid; v < AV; v += 256) {
            int m = v / KQ, kq = v % KQ;
            float4 av = *(const float4*)&A[(size_t)(m0 + m) * K + k0 + kq * 4];
            As[kq * 4 + 0][m] = av.x;
            As[kq * 4 + 1][m] = av.y;
            As[kq * 4 + 2][m] = av.z;
            As[kq * 4 + 3][m] = av.w;
        }
        constexpr int BV = BK * 16;
        for (int v = tid; v < BV; v += 256) {
            int ki = v / 16, nq = v % 16;
            int j = n0 + nq * 4;
            float4 bv = make_float4(0.f, 0.f, 0.f, 0.f);
            if (j < Wout) {
                int wc = (j < Hg) ? (z0 + j) : (f0 + (j - Hg));
                bv = *(const float4*)&W[(size_t)(k0 + ki) * Nfull + wc];
            }
            *(float4*)&Bs[ki][nq * 4] = bv;
        }
        __syncthreads();
#pragma unroll
        for (int kk = 0; kk < BK; ++kk) {
            float a[4];
#pragma unroll
            for (int i = 0; i < 4; ++i) a[i] = As[kk][ty * 4 + i];
            float4 bv = *(const float4*)&Bs[kk][tx * 4];
            float bb[4] = {bv.x, bv.y, bv.z, bv.w};
#pragma unroll
            for (int i = 0; i < 4; ++i)
#pragma unroll
                for (int j = 0; j < 4; ++j) acc[i][j] = fmaf(a[i], bb[j], acc[i][j]);
        }
        __syncthreads();
    }
    int jb = n0 + tx * 4;
    if (jb < Wout) {
        bool isz = jb < Hg;
#pragma unroll
        for (int i = 0; i < 4; ++i) {
            int gm = m0 + ty * 4 + i;
            float o[4];
#pragma unroll
            for (int jj = 0; jj < 4; ++jj) {
                int j = jb + jj;
                int wc = isz ? (z0 + j) : (f0 + (j - Hg));
                float v = acc[i][jj] + bias[wc];
                o[jj] = isz ? fast_tanh(v) : fast_sigmoid(v);
            }
            *(float4*)&ZF[(size_t)gm * Wout + jb] = make_float4(o[0], o[1], o[2], o[3]);
        }
    }
}

// ---------------- fo-pool scan (layers 1-4), chunked with warmup ----------------
__global__ void scan_kernel(const float* __restrict__ zf, float* __restrict__ hout,
                            int Hg, int W2, int Hfull, int ch0) {
    int id = blockIdx.x * blockDim.x + threadIdx.x;
    int total = Bb * NCH * Hg;
    if (id >= total) return;
    int c = id % Hg;
    int p = id / Hg;
    int b = p / NCH, ck = p % NCH;
    int sc = ck * CLEN;
    float h = 0.f;
    if (ck) {
#pragma unroll 4
        for (int s = sc - WARM; s < sc; ++s) {
            size_t base = (size_t)(b * Ss + s) * W2;
            float z = zf[base + c], f = zf[base + Hg + c];
            h = fmaf(f, h - z, z);
        }
    }
#pragma unroll 5
    for (int s = sc; s < sc + CLEN; ++s) {
        size_t base = (size_t)(b * Ss + s) * W2;
        float z = zf[base + c], f = zf[base + Hg + c];
        h = fmaf(f, h - z, z);
        hout[(size_t)(b * Ss + s) * Hfull + ch0 + c] = h;
    }
}

// ---------------- L5 scan fused with mean-pool over channels ----------------
template <int HG>
__global__ void scan_pool_kernel(const float* __restrict__ zf, float* __restrict__ pooled,
                                 int initflag) {
    constexpr int W2 = 2 * HG;
    constexpr int WIN = 50;
    __shared__ float tile[WIN][HG + 1];
    int b = blockIdx.x, ck = blockIdx.y;
    int c = threadIdx.x;
    int sc = ck * CLEN;
    float h = 0.f;
    if (ck) {
#pragma unroll 4
        for (int s = sc - WARM; s < sc; ++s) {
            size_t base = (size_t)(b * Ss + s) * W2;
            float z = zf[base + c], f = zf[base + HG + c];
            h = fmaf(f, h - z, z);
        }
    }
    for (int w0 = 0; w0 < CLEN; w0 += WIN) {
#pragma unroll 5
        for (int r = 0; r < WIN; ++r) {
            size_t base = (size_t)(b * Ss + sc + w0 + r) * W2;
            float z = zf[base + c], f = zf[base + HG + c];
            h = fmaf(f, h - z, z);
            tile[r][c] = h;
        }
        __syncthreads();
#pragma unroll
        for (int stride = HG >> 1; stride >= 1; stride >>= 1) {
            for (int idx = c; idx < WIN * stride; idx += HG) {
                int r = idx / stride, cc = idx % stride;
                tile[r][cc] += tile[r][cc + stride];
            }
            __syncthreads();
        }
        if (c < WIN) {
            size_t po = (size_t)b * Ss + sc + w0 + c;
            float v = tile[c][0] * (1.f / 256.f);
            if (initflag) pooled[po] = v;
            else pooled[po] += v;
        }
        __syncthreads();
    }
}

// ---------------- MLP ----------------
__global__ __launch_bounds__(256) void mlp1_kernel(const float* __restrict__ xp,
                                                   const float* __restrict__ w1,
                                                   float* __restrict__ parts) {
    const int n0 = blockIdx.x * 64;
    const int ks = blockIdx.y;
    const int kbeg = ks * 250;
    const int nl = threadIdx.x % 64, mg = threadIdx.x / 64;
    __shared__ float xs[50][68];
    float acc[16] = {};
    for (int kc = 0; kc < 5; ++kc) {
        int k0 = kbeg + kc * 50;
        __syncthreads();
        for (int idx = threadIdx.x; idx < 64 * 50; idx += 256) {
            int r = idx / 50, cc = idx % 50;
            xs[cc][r] = xp[r * Ss + k0 + cc];
        }
        __syncthreads();
#pragma unroll 5
        for (int kk = 0; kk < 50; ++kk) {
            float wv = w1[(size_t)(k0 + kk) * 1024 + n0 + nl];
#pragma unroll
            for (int q = 0; q < 4; ++q) {
                float4 xv = *(const float4*)&xs[kk][mg * 16 + q * 4];
                acc[q * 4 + 0] = fmaf(xv.x, wv, acc[q * 4 + 0]);
                acc[q * 4 + 1] = fmaf(xv.y, wv, acc[q * 4 + 1]);
                acc[q * 4 + 2] = fmaf(xv.z, wv, acc[q * 4 + 2]);
                acc[q * 4 + 3] = fmaf(xv.w, wv, acc[q * 4 + 3]);
            }
        }
    }
#pragma unroll
    for (int i = 0; i < 16; ++i) {
        int m = mg * 16 + i;
        parts[((size_t)ks * 64 + m) * 1024 + n0 + nl] = acc[i];
    }
}

__global__ void mlp1_reduce(const float* __restrict__ parts, const float* __restrict__ b1,
                            float* __restrict__ h1) {
    int id = blockIdx.x * 256 + threadIdx.x;
    int n = id % 1024, m = id / 1024;
    float s = b1[n];
#pragma unroll
    for (int ks = 0; ks < 12; ++ks) s += parts[((size_t)ks * 64 + m) * 1024 + n];
    h1[id] = fmaxf(s, 0.f);
}

__global__ void mlp2_kernel(const float* __restrict__ h1, const float* __restrict__ w2,
                            const float* __restrict__ b2, float* __restrict__ h2) {
    int m = blockIdx.x, n = threadIdx.x;
    float acc = 0.f;
#pragma unroll 8
    for (int k = 0; k < 1024; ++k) acc = fmaf(h1[m * 1024 + k], w2[k * 128 + n], acc);
    h2[m * 128 + n] = fmaxf(acc + b2[n], 0.f);
}

__global__ void mlp3_kernel(const float* __restrict__ h2, const float* __restrict__ w3,
                            const float* __restrict__ b3, float* __restrict__ out) {
    int t = threadIdx.x;
    if (t >= 640) return;
    int m = t / 10, n = t % 10;
    float acc = 0.f;
#pragma unroll
    for (int k = 0; k < 128; ++k) acc = fmaf(h2[m * 128 + k], w3[k * 10 + n], acc);
    out[t] = fmaxf(acc + b3[n], 0.f);
}

// ---------------- launcher ----------------
extern "C" void kernel_launch(void* const* d_in, const int* in_sizes, int n_in,
                              void* d_out, int out_size, void* d_ws, size_t ws_size,
                              hipStream_t stream) {
    const float* x   = (const float*)d_in[0];
    const float* wih = (const float*)d_in[1];
    const float* whh = (const float*)d_in[2];
    const float* bih = (const float*)d_in[3];
    const float* bhh = (const float*)d_in[4];
    const float* qw[5] = {(const float*)d_in[5], (const float*)d_in[7], (const float*)d_in[9],
                          (const float*)d_in[11], (const float*)d_in[13]};
    const float* qb[5] = {(const float*)d_in[6], (const float*)d_in[8], (const float*)d_in[10],
                          (const float*)d_in[12], (const float*)d_in[14]};
    const float* w1 = (const float*)d_in[15];
    const float* b1 = (const float*)d_in[16];
    const float* w2 = (const float*)d_in[17];
    const float* b2 = (const float*)d_in[18];
    const float* w3 = (const float*)d_in[19];
    const float* b3 = (const float*)d_in[20];
    float* out = (float*)d_out;

    const size_t hA_sz = (size_t)Mm * 128 * 4;
    const size_t hB_sz = (size_t)Mm * 64 * 4;
    const size_t pooled_sz = (size_t)Bb * Ss * 4;
    const size_t parts_sz = 12ull * 64 * 1024 * 4;
    const size_t h1_sz = 64ull * 1024 * 4;
    const size_t h2_sz = 64ull * 128 * 4;
    const size_t tail = pooled_sz + parts_sz + h1_sz + h2_sz;

    int G[5] = {1, 1, 1, 1, 2};
    size_t zf_sz = (size_t)Mm * 256 * 4;
    if (ws_size < hA_sz + hB_sz + zf_sz + tail) {
        G[3] = 2; G[4] = 4; zf_sz = (size_t)Mm * 128 * 4;
    }
    if (ws_size < hA_sz + hB_sz + zf_sz + tail) {
        G[2] = 2; G[3] = 4; G[4] = 8; zf_sz = (size_t)Mm * 64 * 4;
    }

    char* ws = (char*)d_ws;
    float* hA = (float*)ws;
    float* hB = (float*)(ws + hA_sz);
    float* zfb = (float*)(ws + hA_sz + hB_sz);
    float* pooled = (float*)(ws + hA_sz + hB_sz + zf_sz);
    float* parts = (float*)(ws + hA_sz + hB_sz + zf_sz + pooled_sz);
    float* h1m = (float*)(ws + hA_sz + hB_sz + zf_sz + pooled_sz + parts_sz);
    float* h2m = (float*)(ws + hA_sz + hB_sz + zf_sz + pooled_sz + parts_sz + h1_sz);

    rnn_kernel2<<<Bb, 64, 0, stream>>>(x, wih, whh, bih, bhh, hA);

    const int Hs[5] = {16, 32, 64, 128, 256};
    const int Ks[5] = {4, 16, 32, 64, 128};
    float* hcur = hA;
    float* hnext = hB;
    for (int L = 0; L < 5; ++L) {
        int H = Hs[L], K = Ks[L], g = G[L], Hg = H / g, Wout = 2 * Hg, Nfull = 2 * H;
        bool mfma_ok = (Wout % 128 == 0) && (K >= 32);
        for (int gi = 0; gi < g; ++gi) {
            int z0 = gi * Hg, f0 = H + gi * Hg;
            if (mfma_ok) {
                dim3 grid(Wout / 128, Mm / 128);
                switch (K) {
                    case 32:  qrnn_gemm_mfma<32><<<grid, 256, 0, stream>>>(hcur, qw[L], qb[L], zfb, Nfull, Wout, Hg, z0, f0); break;
                    case 64:  qrnn_gemm_mfma<64><<<grid, 256, 0, stream>>>(hcur, qw[L], qb[L], zfb, Nfull, Wout, Hg, z0, f0); break;
                    default:  qrnn_gemm_mfma<128><<<grid, 256, 0, stream>>>(hcur, qw[L], qb[L], zfb, Nfull, Wout, Hg, z0, f0); break;
                }
            } else {
                dim3 grid(Mm / 64, (Wout + 63) / 64);
                switch (K) {
                    case 4:   qrnn_gemm<4><<<grid, 256, 0, stream>>>(hcur, qw[L], qb[L], zfb, Nfull, Wout, Hg, z0, f0); break;
                    case 16:  qrnn_gemm<16><<<grid, 256, 0, stream>>>(hcur, qw[L], qb[L], zfb, Nfull, Wout, Hg, z0, f0); break;
                    case 32:  qrnn_gemm<32><<<grid, 256, 0, stream>>>(hcur, qw[L], qb[L], zfb, Nfull, Wout, Hg, z0, f0); break;
                    case 64:  qrnn_gemm<64><<<grid, 256, 0, stream>>>(hcur, qw[L], qb[L], zfb, Nfull, Wout, Hg, z0, f0); break;
                    default:  qrnn_gemm<128><<<grid, 256, 0, stream>>>(hcur, qw[L], qb[L], zfb, Nfull, Wout, Hg, z0, f0); break;
                }
            }
            if (L < 4) {
                int total = Bb * NCH * Hg;
                scan_kernel<<<(total + 255) / 256, 256, 0, stream>>>(zfb, hnext, Hg, Wout, H, z0);
            } else {
                dim3 g2(Bb, NCH);
                if (Hg == 128)      scan_pool_kernel<128><<<g2, 128, 0, stream>>>(zfb, pooled, gi == 0);
                else if (Hg == 64)  scan_pool_kernel<64><<<g2, 64, 0, stream>>>(zfb, pooled, gi == 0);
                else                scan_pool_kernel<32><<<g2, 32, 0, stream>>>(zfb, pooled, gi == 0);
            }
        }
        if (L < 4) { float* t = hcur; hcur = hnext; hnext = t; }
    }

    mlp1_kernel<<<dim3(16, 12), 256, 0, stream>>>(pooled, w1, parts);
    mlp1_reduce<<<256, 256, 0, stream>>>(parts, b1, h1m);
    mlp2_kernel<<<64, 128, 0, stream>>>(h1m, w2, b2, h2m);
    mlp3_kernel<<<1, 640, 0, stream>>>(h2m, w3, b3, out);
    (void)in_sizes; (void)n_in; (void)out_size;
}

// Round 4
// 744.666 us; speedup vs baseline: 1.8926x; 1.4228x over previous
//
#include <hip/hip_runtime.h>

#define DEVI __device__ __forceinline__

static constexpr int Bb = 64;
static constexpr int Ss = 3000;
static constexpr int Mm = Bb * Ss;      // 192000
static constexpr int NCH = 12;          // sequence chunks (scans)
static constexpr int CLEN = 250;        // chunk length (scans)
static constexpr int WARM = 64;         // scan warmup steps
static constexpr int RCH = 60;          // rnn chunks
static constexpr int RCLEN = 50;        // rnn chunk length
static constexpr int RWARM = 32;        // rnn warmup steps

typedef short bs8 __attribute__((ext_vector_type(8)));
typedef float f32x4 __attribute__((ext_vector_type(4)));

DEVI float fast_tanh(float x) {
    float e = __expf(2.0f * x);
    return 1.0f - 2.0f / (e + 1.0f);
}
DEVI float fast_sigmoid(float x) {
    return 1.0f / (1.0f + __expf(-x));
}
DEVI unsigned short f2bf(float f) {
    unsigned u = __float_as_uint(f);
    u += 0x7FFF + ((u >> 16) & 1);
    return (unsigned short)(u >> 16);
}
DEVI float bf2f(unsigned short h) { return __uint_as_float(((unsigned)h) << 16); }

// ---------------- RNN (hidden=4): LDS-staged x, 60 chunks/batch ----------------
__global__ __launch_bounds__(64) void rnn_kernel2(const float* __restrict__ x,
                                                  const float* __restrict__ wih,
                                                  const float* __restrict__ whh,
                                                  const float* __restrict__ bih,
                                                  const float* __restrict__ bhh,
                                                  float* __restrict__ hout) {
    __shared__ float xs[Ss];
    int b = blockIdx.x;
    for (int i = threadIdx.x; i < Ss / 4; i += 64) {
        *(float4*)&xs[i * 4] = *(const float4*)&x[b * Ss + i * 4];
    }
    __syncthreads();
    int ck = threadIdx.x;
    if (ck >= RCH) return;
    float w[4][4], wi[4], bc[4];
#pragma unroll
    for (int j = 0; j < 4; ++j) {
        wi[j] = wih[j];
        bc[j] = bih[j] + bhh[j];
#pragma unroll
        for (int i = 0; i < 4; ++i) w[j][i] = whh[j * 4 + i];
    }
    float h0 = 0.f, h1 = 0.f, h2 = 0.f, h3 = 0.f;
    int sc = ck * RCLEN;
    int sb = ck ? (sc - RWARM) : 0;
#pragma unroll 4
    for (int s = sb; s < sc; ++s) {
        float xv = xs[s];
        float n0 = fast_tanh(fmaf(xv, wi[0], bc[0]) + w[0][0]*h0 + w[0][1]*h1 + w[0][2]*h2 + w[0][3]*h3);
        float n1 = fast_tanh(fmaf(xv, wi[1], bc[1]) + w[1][0]*h0 + w[1][1]*h1 + w[1][2]*h2 + w[1][3]*h3);
        float n2 = fast_tanh(fmaf(xv, wi[2], bc[2]) + w[2][0]*h0 + w[2][1]*h1 + w[2][2]*h2 + w[2][3]*h3);
        float n3 = fast_tanh(fmaf(xv, wi[3], bc[3]) + w[3][0]*h0 + w[3][1]*h1 + w[3][2]*h2 + w[3][3]*h3);
        h0 = n0; h1 = n1; h2 = n2; h3 = n3;
    }
#pragma unroll 5
    for (int s = sc; s < sc + RCLEN; ++s) {
        float xv = xs[s];
        float n0 = fast_tanh(fmaf(xv, wi[0], bc[0]) + w[0][0]*h0 + w[0][1]*h1 + w[0][2]*h2 + w[0][3]*h3);
        float n1 = fast_tanh(fmaf(xv, wi[1], bc[1]) + w[1][0]*h0 + w[1][1]*h1 + w[1][2]*h2 + w[1][3]*h3);
        float n2 = fast_tanh(fmaf(xv, wi[2], bc[2]) + w[2][0]*h0 + w[2][1]*h1 + w[2][2]*h2 + w[2][3]*h3);
        float n3 = fast_tanh(fmaf(xv, wi[3], bc[3]) + w[3][0]*h0 + w[3][1]*h1 + w[3][2]*h2 + w[3][3]*h3);
        h0 = n0; h1 = n1; h2 = n2; h3 = n3;
        *(float4*)&hout[(size_t)(b * Ss + s) * 4] = make_float4(h0, h1, h2, h3);
    }
}

// ---------------- weight prep: W (K,2H) fp32 -> transposed bf16 hi/lo planes [2H][K] ----------------
__global__ void prep_w(const float* __restrict__ W, short* __restrict__ Wh,
                       short* __restrict__ Wl, int K, int N2) {
    int total = K * N2;
    for (int t = blockIdx.x * blockDim.x + threadIdx.x; t < total; t += gridDim.x * blockDim.x) {
        int n = t / K, k = t % K;
        float w = W[(size_t)k * N2 + n];
        unsigned short h = f2bf(w);
        Wh[(size_t)n * K + k] = (short)h;
        Wl[(size_t)n * K + k] = (short)f2bf(w - bf2f(h));
    }
}

// ---------------- LDS-free MFMA GEMM ----------------
// A: bf16 plane [Mm][K].  W: bf16 hi/lo planes [2H][K] (transposed).
// Output ZFP packed u32 [Mm][Hgp]: hi16 = bf16(tanh(z+bz)), lo16 = bf16(sigmoid(f+bf)).
// 2-term split: A_bf16 * (W_hi + W_lo)  (W at ~fp32 precision, A at bf16).
// Fragment k-mapping (free bijection, consistent A/B): lane l, reg j -> k = s*32 + (l>>4)*8 + j.
// C/D layout (HW): col = lane&15 (within col-frag), row = (lane>>4)*4 + r.
template <int K>
__global__ __launch_bounds__(256) void qrnn_gemm_mfma2(const short* __restrict__ Ah,
                                                       const short* __restrict__ Wh,
                                                       const short* __restrict__ Wl,
                                                       const float* __restrict__ bias,
                                                       unsigned* __restrict__ ZFP,
                                                       int Hgp, int wz0, int wf0) {
    const int tid = threadIdx.x;
    const int lane = tid & 63;
    const int wid = tid >> 6;
    const int wr = wid >> 1, wc = wid & 1;
    const int m0 = blockIdx.y * 128;
    const int cb0 = blockIdx.x * 64 + wc * 32;
    const int l15 = lane & 15, lh = lane >> 4;
    const int kbase = lh * 8;

    f32x4 acc[4][4] = {};

#pragma unroll
    for (int s = 0; s < K / 32; ++s) {
        bs8 ah[4], bh[4], bl[4];
#pragma unroll
        for (int i = 0; i < 4; ++i) {
            size_t off = (size_t)(m0 + wr * 64 + i * 16 + l15) * K + s * 32 + kbase;
            ah[i] = *(const bs8*)&Ah[off];
        }
#pragma unroll
        for (int q = 0; q < 2; ++q) {
            int cq = cb0 + q * 16 + l15;
            size_t oz = (size_t)(wz0 + cq) * K + s * 32 + kbase;
            size_t of = (size_t)(wf0 + cq) * K + s * 32 + kbase;
            bh[q * 2 + 0] = *(const bs8*)&Wh[oz];
            bl[q * 2 + 0] = *(const bs8*)&Wl[oz];
            bh[q * 2 + 1] = *(const bs8*)&Wh[of];
            bl[q * 2 + 1] = *(const bs8*)&Wl[of];
        }
#pragma unroll
        for (int i = 0; i < 4; ++i)
#pragma unroll
            for (int j = 0; j < 4; ++j) {
                acc[i][j] = __builtin_amdgcn_mfma_f32_16x16x32_bf16(ah[i], bh[j], acc[i][j], 0, 0, 0);
                acc[i][j] = __builtin_amdgcn_mfma_f32_16x16x32_bf16(ah[i], bl[j], acc[i][j], 0, 0, 0);
            }
    }
    // epilogue: bias + activations + pack (z,f) -> u32
#pragma unroll
    for (int q = 0; q < 2; ++q) {
        int cq = cb0 + q * 16 + l15;
        float bz = bias[wz0 + cq];
        float bf = bias[wf0 + cq];
#pragma unroll
        for (int i = 0; i < 4; ++i) {
            int row0 = m0 + wr * 64 + i * 16 + lh * 4;
#pragma unroll
            for (int r = 0; r < 4; ++r) {
                float zv = fast_tanh(acc[i][q * 2 + 0][r] + bz);
                float fv = fast_sigmoid(acc[i][q * 2 + 1][r] + bf);
                unsigned u = ((unsigned)f2bf(zv) << 16) | (unsigned)f2bf(fv);
                ZFP[(size_t)(row0 + r) * Hgp + cq] = u;
            }
        }
    }
}

// ---------------- small fp32 GEMM (layers with K<32) ----------------
template <int K>
__global__ __launch_bounds__(256) void qrnn_gemm(const float* __restrict__ A,
                                                 const float* __restrict__ W,
                                                 const float* __restrict__ bias,
                                                 float* __restrict__ ZF,
                                                 int Nfull, int Wout, int Hg, int z0, int f0) {
    constexpr int BM = 64, BN = 64;
    constexpr int BK = (K < 32) ? K : 32;
    __shared__ float As[BK][BM + 4];
    __shared__ float Bs[BK][BN];
    const int tid = threadIdx.x;
    const int tx = tid % 16, ty = tid / 16;
    const int m0 = blockIdx.x * BM;
    const int n0 = blockIdx.y * BN;
    float acc[4][4] = {};

    for (int k0 = 0; k0 < K; k0 += BK) {
        constexpr int KQ = BK / 4;
        constexpr int AV = BM * KQ;
        for (int v = tid; v < AV; v += 256) {
            int m = v / KQ, kq = v % KQ;
            float4 av = *(const float4*)&A[(size_t)(m0 + m) * K + k0 + kq * 4];
            As[kq * 4 + 0][m] = av.x;
            As[kq * 4 + 1][m] = av.y;
            As[kq * 4 + 2][m] = av.z;
            As[kq * 4 + 3][m] = av.w;
        }
        constexpr int BV = BK * 16;
        for (int v = tid; v < BV; v += 256) {
            int ki = v / 16, nq = v % 16;
            int j = n0 + nq * 4;
            float4 bv = make_float4(0.f, 0.f, 0.f, 0.f);
            if (j < Wout) {
                int wc = (j < Hg) ? (z0 + j) : (f0 + (j - Hg));
                bv = *(const float4*)&W[(size_t)(k0 + ki) * Nfull + wc];
            }
            *(float4*)&Bs[ki][nq * 4] = bv;
        }
        __syncthreads();
#pragma unroll
        for (int kk = 0; kk < BK; ++kk) {
            float a[4];
#pragma unroll
            for (int i = 0; i < 4; ++i) a[i] = As[kk][ty * 4 + i];
            float4 bv = *(const float4*)&Bs[kk][tx * 4];
            float bb[4] = {bv.x, bv.y, bv.z, bv.w};
#pragma unroll
            for (int i = 0; i < 4; ++i)
#pragma unroll
                for (int j = 0; j < 4; ++j) acc[i][j] = fmaf(a[i], bb[j], acc[i][j]);
        }
        __syncthreads();
    }
    int jb = n0 + tx * 4;
    if (jb < Wout) {
        bool isz = jb < Hg;
#pragma unroll
        for (int i = 0; i < 4; ++i) {
            int gm = m0 + ty * 4 + i;
            float o[4];
#pragma unroll
            for (int jj = 0; jj < 4; ++jj) {
                int j = jb + jj;
                int wc = isz ? (z0 + j) : (f0 + (j - Hg));
                float v = acc[i][jj] + bias[wc];
                o[jj] = isz ? fast_tanh(v) : fast_sigmoid(v);
            }
            *(float4*)&ZF[(size_t)gm * Wout + jb] = make_float4(o[0], o[1], o[2], o[3]);
        }
    }
}

// ---------------- scans ----------------
// fp32 zf -> fp32 compact h (after layer0)
__global__ void scan_f2c(const float* __restrict__ zf, float* __restrict__ hout,
                         int Hg, int W2, int Hfull, int ch0) {
    int id = blockIdx.x * blockDim.x + threadIdx.x;
    int total = Bb * NCH * Hg;
    if (id >= total) return;
    int c = id % Hg;
    int p = id / Hg;
    int b = p / NCH, ck = p % NCH;
    int sc = ck * CLEN;
    float h = 0.f;
    if (ck) {
#pragma unroll 4
        for (int s = sc - WARM; s < sc; ++s) {
            size_t base = (size_t)(b * Ss + s) * W2;
            float z = zf[base + c], f = zf[base + Hg + c];
            h = fmaf(f, h - z, z);
        }
    }
#pragma unroll 5
    for (int s = sc; s < sc + CLEN; ++s) {
        size_t base = (size_t)(b * Ss + s) * W2;
        float z = zf[base + c], f = zf[base + Hg + c];
        h = fmaf(f, h - z, z);
        hout[(size_t)(b * Ss + s) * Hfull + ch0 + c] = h;
    }
}

// fp32 zf -> bf16 plane (after layer1)
__global__ void scan_f2p(const float* __restrict__ zf, short* __restrict__ Ahp,
                         int Hg, int W2, int Kn, int ch0) {
    int id = blockIdx.x * blockDim.x + threadIdx.x;
    int total = Bb * NCH * Hg;
    if (id >= total) return;
    int c = id % Hg;
    int p = id / Hg;
    int b = p / NCH, ck = p % NCH;
    int sc = ck * CLEN;
    float h = 0.f;
    if (ck) {
#pragma unroll 4
        for (int s = sc - WARM; s < sc; ++s) {
            size_t base = (size_t)(b * Ss + s) * W2;
            float z = zf[base + c], f = zf[base + Hg + c];
            h = fmaf(f, h - z, z);
        }
    }
#pragma unroll 5
    for (int s = sc; s < sc + CLEN; ++s) {
        size_t base = (size_t)(b * Ss + s) * W2;
        float z = zf[base + c], f = zf[base + Hg + c];
        h = fmaf(f, h - z, z);
        Ahp[(size_t)(b * Ss + s) * Kn + ch0 + c] = (short)f2bf(h);
    }
}

// packed zf -> bf16 plane (after layers 2,3)
__global__ void scan_p2p(const unsigned* __restrict__ zfp, short* __restrict__ Ahp, int Hc) {
    int id = blockIdx.x * blockDim.x + threadIdx.x;
    int total = Bb * NCH * Hc;
    if (id >= total) return;
    int c = id % Hc;
    int p = id / Hc;
    int b = p / NCH, ck = p % NCH;
    int sc = ck * CLEN;
    float h = 0.f;
    if (ck) {
#pragma unroll 4
        for (int s = sc - WARM; s < sc; ++s) {
            unsigned u = zfp[(size_t)(b * Ss + s) * Hc + c];
            float z = bf2f((unsigned short)(u >> 16));
            float f = bf2f((unsigned short)(u & 0xFFFF));
            h = fmaf(f, h - z, z);
        }
    }
#pragma unroll 5
    for (int s = sc; s < sc + CLEN; ++s) {
        unsigned u = zfp[(size_t)(b * Ss + s) * Hc + c];
        float z = bf2f((unsigned short)(u >> 16));
        float f = bf2f((unsigned short)(u & 0xFFFF));
        h = fmaf(f, h - z, z);
        Ahp[(size_t)(b * Ss + s) * Hc + c] = (short)f2bf(h);
    }
}

// packed zf -> fo-pool scan fused with mean over channels (layer 4)
template <int HG>
__global__ void scan_pool_p(const unsigned* __restrict__ zfp, float* __restrict__ pooled,
                            int initflag) {
    constexpr int WIN = 50;
    __shared__ float tile[WIN][HG + 1];
    int b = blockIdx.x, ck = blockIdx.y;
    int c = threadIdx.x;
    int sc = ck * CLEN;
    float h = 0.f;
    if (ck) {
#pragma unroll 4
        for (int s = sc - WARM; s < sc; ++s) {
            unsigned u = zfp[(size_t)(b * Ss + s) * HG + c];
            float z = bf2f((unsigned short)(u >> 16));
            float f = bf2f((unsigned short)(u & 0xFFFF));
            h = fmaf(f, h - z, z);
        }
    }
    for (int w0 = 0; w0 < CLEN; w0 += WIN) {
#pragma unroll 5
        for (int r = 0; r < WIN; ++r) {
            unsigned u = zfp[(size_t)(b * Ss + sc + w0 + r) * HG + c];
            float z = bf2f((unsigned short)(u >> 16));
            float f = bf2f((unsigned short)(u & 0xFFFF));
            h = fmaf(f, h - z, z);
            tile[r][c] = h;
        }
        __syncthreads();
#pragma unroll
        for (int stride = HG >> 1; stride >= 1; stride >>= 1) {
            for (int idx = c; idx < WIN * stride; idx += HG) {
                int rr = idx / stride, cc = idx % stride;
                tile[rr][cc] += tile[rr][cc + stride];
            }
            __syncthreads();
        }
        if (c < WIN) {
            size_t po = (size_t)b * Ss + sc + w0 + c;
            float v = tile[c][0] * (1.f / 256.f);
            if (initflag) pooled[po] = v;
            else pooled[po] += v;
        }
        __syncthreads();
    }
}

// ---------------- MLP ----------------
__global__ __launch_bounds__(256) void mlp1_kernel(const float* __restrict__ xp,
                                                   const float* __restrict__ w1,
                                                   float* __restrict__ parts) {
    const int n0 = blockIdx.x * 64;
    const int ks = blockIdx.y;
    const int kbeg = ks * 250;
    const int nl = threadIdx.x % 64, mg = threadIdx.x / 64;
    __shared__ float xs[50][68];
    float acc[16] = {};
    for (int kc = 0; kc < 5; ++kc) {
        int k0 = kbeg + kc * 50;
        __syncthreads();
        for (int idx = threadIdx.x; idx < 64 * 50; idx += 256) {
            int r = idx / 50, cc = idx % 50;
            xs[cc][r] = xp[r * Ss + k0 + cc];
        }
        __syncthreads();
#pragma unroll 5
        for (int kk = 0; kk < 50; ++kk) {
            float wv = w1[(size_t)(k0 + kk) * 1024 + n0 + nl];
#pragma unroll
            for (int q = 0; q < 4; ++q) {
                float4 xv = *(const float4*)&xs[kk][mg * 16 + q * 4];
                acc[q * 4 + 0] = fmaf(xv.x, wv, acc[q * 4 + 0]);
                acc[q * 4 + 1] = fmaf(xv.y, wv, acc[q * 4 + 1]);
                acc[q * 4 + 2] = fmaf(xv.z, wv, acc[q * 4 + 2]);
                acc[q * 4 + 3] = fmaf(xv.w, wv, acc[q * 4 + 3]);
            }
        }
    }
#pragma unroll
    for (int i = 0; i < 16; ++i) {
        int m = mg * 16 + i;
        parts[((size_t)ks * 64 + m) * 1024 + n0 + nl] = acc[i];
    }
}

__global__ void mlp1_reduce(const float* __restrict__ parts, const float* __restrict__ b1,
                            float* __restrict__ h1) {
    int id = blockIdx.x * 256 + threadIdx.x;
    int n = id % 1024, m = id / 1024;
    float s = b1[n];
#pragma unroll
    for (int ks = 0; ks < 12; ++ks) s += parts[((size_t)ks * 64 + m) * 1024 + n];
    h1[id] = fmaxf(s, 0.f);
}

__global__ void mlp2_kernel(const float* __restrict__ h1, const float* __restrict__ w2,
                            const float* __restrict__ b2, float* __restrict__ h2) {
    int m = blockIdx.x, n = threadIdx.x;
    float acc = 0.f;
#pragma unroll 8
    for (int k = 0; k < 1024; ++k) acc = fmaf(h1[m * 1024 + k], w2[k * 128 + n], acc);
    h2[m * 128 + n] = fmaxf(acc + b2[n], 0.f);
}

__global__ void mlp3_kernel(const float* __restrict__ h2, const float* __restrict__ w3,
                            const float* __restrict__ b3, float* __restrict__ out) {
    int t = threadIdx.x;
    if (t >= 640) return;
    int m = t / 10, n = t % 10;
    float acc = 0.f;
#pragma unroll
    for (int k = 0; k < 128; ++k) acc = fmaf(h2[m * 128 + k], w3[k * 10 + n], acc);
    out[t] = fmaxf(acc + b3[n], 0.f);
}

// ---------------- launcher ----------------
extern "C" void kernel_launch(void* const* d_in, const int* in_sizes, int n_in,
                              void* d_out, int out_size, void* d_ws, size_t ws_size,
                              hipStream_t stream) {
    const float* x   = (const float*)d_in[0];
    const float* wih = (const float*)d_in[1];
    const float* whh = (const float*)d_in[2];
    const float* bih = (const float*)d_in[3];
    const float* bhh = (const float*)d_in[4];
    const float* qw[5] = {(const float*)d_in[5], (const float*)d_in[7], (const float*)d_in[9],
                          (const float*)d_in[11], (const float*)d_in[13]};
    const float* qb[5] = {(const float*)d_in[6], (const float*)d_in[8], (const float*)d_in[10],
                          (const float*)d_in[12], (const float*)d_in[14]};
    const float* w1 = (const float*)d_in[15];
    const float* b1 = (const float*)d_in[16];
    const float* w2 = (const float*)d_in[17];
    const float* b2 = (const float*)d_in[18];
    const float* w3 = (const float*)d_in[19];
    const float* b3 = (const float*)d_in[20];
    float* out = (float*)d_out;

    // ---- ws carve (sizes in bytes, 256-aligned) ----
    auto al = [](size_t v) { return (v + 255) & ~size_t(255); };
    const size_t h1_sz    = al((size_t)Mm * 128 * 2);   // 49.2 MB: plane K=128 / fp32 [Mm][4] / plane K=32
    const size_t h2_sz    = al((size_t)Mm * 64 * 2);    // 24.6 MB: plane K=64  / fp32 [Mm][16]
    const size_t pooled_sz = al((size_t)Bb * Ss * 4);
    const size_t parts_sz = al(12ull * 64 * 1024 * 4);
    const size_t h1m_sz   = al(64ull * 1024 * 4);
    const size_t h2m_sz   = al(64ull * 128 * 4);
    const size_t wp_sz    = al((4096ull + 4096 + 16384 + 16384 + 65536 + 65536) * 2);
    const size_t tail     = pooled_sz + parts_sz + h1m_sz + h2m_sz + wp_sz;

    size_t zf_full = al((size_t)Mm * 256 * 4);          // 196.6 MB (layer4 G=1 packed)
    size_t zf_half = al((size_t)Mm * 128 * 4);          // 98.3 MB (layer4 G=2 packed)
    int G5 = (ws_size >= h1_sz + h2_sz + zf_full + tail) ? 1 : 2;
    size_t zf_sz = (G5 == 1) ? zf_full : zf_half;

    char* ws = (char*)d_ws;
    char* p = ws;
    char* hbuf1 = p; p += h1_sz;
    char* hbuf2 = p; p += h2_sz;
    char* zfb   = p; p += zf_sz;
    float* pooled = (float*)p; p += pooled_sz;
    float* parts  = (float*)p; p += parts_sz;
    float* h1m    = (float*)p; p += h1m_sz;
    float* h2m    = (float*)p; p += h2m_sz;
    short* wp     = (short*)p;
    short* wh2 = wp;            short* wl2 = wh2 + 4096;
    short* wh3 = wl2 + 4096;    short* wl3 = wh3 + 16384;
    short* wh4 = wl3 + 16384;   short* wl4 = wh4 + 65536;

    float*    zf32 = (float*)zfb;
    unsigned* zfp  = (unsigned*)zfb;

    // ---- weight prep (tiny) ----
    prep_w<<<16, 256, 0, stream>>>(qw[2], wh2, wl2, 32, 128);
    prep_w<<<16, 256, 0, stream>>>(qw[3], wh3, wl3, 64, 256);
    prep_w<<<32, 256, 0, stream>>>(qw[4], wh4, wl4, 128, 512);

    // ---- RNN -> hbuf1 (fp32 [Mm][4]) ----
    rnn_kernel2<<<Bb, 64, 0, stream>>>(x, wih, whh, bih, bhh, (float*)hbuf1);

    // ---- layer0 (K=4, H=16): small gemm fp32 + scan -> hbuf2 fp32 [Mm][16] ----
    {
        dim3 grid(Mm / 64, 1);
        qrnn_gemm<4><<<grid, 256, 0, stream>>>((const float*)hbuf1, qw[0], qb[0], zf32, 32, 32, 16, 0, 16);
        int total = Bb * NCH * 16;
        scan_f2c<<<(total + 255) / 256, 256, 0, stream>>>(zf32, (float*)hbuf2, 16, 32, 16, 0);
    }
    // ---- layer1 (K=16, H=32): small gemm fp32 + scan -> bf16 plane [Mm][32] in hbuf1 ----
    {
        dim3 grid(Mm / 64, 1);
        qrnn_gemm<16><<<grid, 256, 0, stream>>>((const float*)hbuf2, qw[1], qb[1], zf32, 64, 64, 32, 0, 32);
        int total = Bb * NCH * 32;
        scan_f2p<<<(total + 255) / 256, 256, 0, stream>>>(zf32, (short*)hbuf1, 32, 64, 32, 0);
    }
    // ---- layer2 (K=32, H=64): MFMA + scan -> plane [Mm][64] in hbuf2 ----
    {
        dim3 grid(1, Mm / 128);
        qrnn_gemm_mfma2<32><<<grid, 256, 0, stream>>>((const short*)hbuf1, wh2, wl2, qb[2], zfp, 64, 0, 64);
        int total = Bb * NCH * 64;
        scan_p2p<<<(total + 255) / 256, 256, 0, stream>>>(zfp, (short*)hbuf2, 64);
    }
    // ---- layer3 (K=64, H=128): MFMA + scan -> plane [Mm][128] in hbuf1 ----
    {
        dim3 grid(2, Mm / 128);
        qrnn_gemm_mfma2<64><<<grid, 256, 0, stream>>>((const short*)hbuf2, wh3, wl3, qb[3], zfp, 128, 0, 128);
        int total = Bb * NCH * 128;
        scan_p2p<<<(total + 255) / 256, 256, 0, stream>>>(zfp, (short*)hbuf1, 128);
    }
    // ---- layer4 (K=128, H=256): MFMA + pool-scan, G5 channel groups ----
    if (G5 == 1) {
        dim3 grid(4, Mm / 128);
        qrnn_gemm_mfma2<128><<<grid, 256, 0, stream>>>((const short*)hbuf1, wh4, wl4, qb[4], zfp, 256, 0, 256);
        dim3 g2(Bb, NCH);
        scan_pool_p<256><<<g2, 256, 0, stream>>>(zfp, pooled, 1);
    } else {
        for (int gi = 0; gi < 2; ++gi) {
            dim3 grid(2, Mm / 128);
            qrnn_gemm_mfma2<128><<<grid, 256, 0, stream>>>((const short*)hbuf1, wh4, wl4, qb[4], zfp,
                                                           128, gi * 128, 256 + gi * 128);
            dim3 g2(Bb, NCH);
            scan_pool_p<128><<<g2, 128, 0, stream>>>(zfp, pooled, gi == 0);
        }
    }

    // ---- MLP ----
    mlp1_kernel<<<dim3(16, 12), 256, 0, stream>>>(pooled, w1, parts);
    mlp1_reduce<<<256, 256, 0, stream>>>(parts, b1, h1m);
    mlp2_kernel<<<64, 128, 0, stream>>>(h1m, w2, b2, h2m);
    mlp3_kernel<<<1, 640, 0, stream>>>(h2m, w3, b3, out);
    (void)in_sizes; (void)n_in; (void)out_size;
}

// Round 9
// 616.329 us; speedup vs baseline: 2.2867x; 1.2082x over previous
//
#include <hip/hip_runtime.h>

#define DEVI __device__ __forceinline__

static constexpr int Bb = 64;
static constexpr int Ss = 3000;
static constexpr int Mm = Bb * Ss;      // 192000
static constexpr int NCH = 12;          // sequence chunks (L0/L1 scans)
static constexpr int CLEN = 250;        // chunk length (L0/L1 scans)
static constexpr int WARM = 64;         // scan warmup steps
static constexpr int NCK = 12;          // fused chunks (256 steps each)
static constexpr int RCH = 60;          // rnn chunks
static constexpr int RCLEN = 50;        // rnn chunk length
static constexpr int RWARM = 32;        // rnn warmup steps

typedef short bs8 __attribute__((ext_vector_type(8)));
typedef float f32x4 __attribute__((ext_vector_type(4)));

DEVI float fast_tanh(float x) {
    float e = __expf(2.0f * x);
    return 1.0f - 2.0f / (e + 1.0f);
}
DEVI float fast_sigmoid(float x) {
    return 1.0f / (1.0f + __expf(-x));
}
DEVI unsigned short f2bf(float f) {
    unsigned u = __float_as_uint(f);
    u += 0x7FFF + ((u >> 16) & 1);
    return (unsigned short)(u >> 16);
}
DEVI float bf2f(unsigned short h) { return __uint_as_float(((unsigned)h) << 16); }

// ---------------- RNN (hidden=4): LDS-staged x, 60 chunks/batch ----------------
__global__ __launch_bounds__(64) void rnn_kernel2(const float* __restrict__ x,
                                                  const float* __restrict__ wih,
                                                  const float* __restrict__ whh,
                                                  const float* __restrict__ bih,
                                                  const float* __restrict__ bhh,
                                                  float* __restrict__ hout) {
    __shared__ float xs[Ss];
    int b = blockIdx.x;
    for (int i = threadIdx.x; i < Ss / 4; i += 64) {
        *(float4*)&xs[i * 4] = *(const float4*)&x[b * Ss + i * 4];
    }
    __syncthreads();
    int ck = threadIdx.x;
    if (ck >= RCH) return;
    float w[4][4], wi[4], bc[4];
#pragma unroll
    for (int j = 0; j < 4; ++j) {
        wi[j] = wih[j];
        bc[j] = bih[j] + bhh[j];
#pragma unroll
        for (int i = 0; i < 4; ++i) w[j][i] = whh[j * 4 + i];
    }
    float h0 = 0.f, h1 = 0.f, h2 = 0.f, h3 = 0.f;
    int sc = ck * RCLEN;
    int sb = ck ? (sc - RWARM) : 0;
#pragma unroll 4
    for (int s = sb; s < sc; ++s) {
        float xv = xs[s];
        float n0 = fast_tanh(fmaf(xv, wi[0], bc[0]) + w[0][0]*h0 + w[0][1]*h1 + w[0][2]*h2 + w[0][3]*h3);
        float n1 = fast_tanh(fmaf(xv, wi[1], bc[1]) + w[1][0]*h0 + w[1][1]*h1 + w[1][2]*h2 + w[1][3]*h3);
        float n2 = fast_tanh(fmaf(xv, wi[2], bc[2]) + w[2][0]*h0 + w[2][1]*h1 + w[2][2]*h2 + w[2][3]*h3);
        float n3 = fast_tanh(fmaf(xv, wi[3], bc[3]) + w[3][0]*h0 + w[3][1]*h1 + w[3][2]*h2 + w[3][3]*h3);
        h0 = n0; h1 = n1; h2 = n2; h3 = n3;
    }
#pragma unroll 5
    for (int s = sc; s < sc + RCLEN; ++s) {
        float xv = xs[s];
        float n0 = fast_tanh(fmaf(xv, wi[0], bc[0]) + w[0][0]*h0 + w[0][1]*h1 + w[0][2]*h2 + w[0][3]*h3);
        float n1 = fast_tanh(fmaf(xv, wi[1], bc[1]) + w[1][0]*h0 + w[1][1]*h1 + w[1][2]*h2 + w[1][3]*h3);
        float n2 = fast_tanh(fmaf(xv, wi[2], bc[2]) + w[2][0]*h0 + w[2][1]*h1 + w[2][2]*h2 + w[2][3]*h3);
        float n3 = fast_tanh(fmaf(xv, wi[3], bc[3]) + w[3][0]*h0 + w[3][1]*h1 + w[3][2]*h2 + w[3][3]*h3);
        h0 = n0; h1 = n1; h2 = n2; h3 = n3;
        *(float4*)&hout[(size_t)(b * Ss + s) * 4] = make_float4(h0, h1, h2, h3);
    }
}

// -------- weight prep: W (K,2H) fp32 -> frag-packed bf16 hi/lo planes --------
// Layout: [frag=n/16][s=k/32][lane=(n&15)|(((k>>3)&3)<<4)][elem=k&7]
__global__ void prep_wfrag(const float* __restrict__ W, short* __restrict__ Wh,
                           short* __restrict__ Wl, int K, int N2) {
    int total = K * N2;
    int NS = K / 32;
    for (int t = blockIdx.x * blockDim.x + threadIdx.x; t < total; t += gridDim.x * blockDim.x) {
        int n = t / K, k = t % K;
        float w = W[(size_t)k * N2 + n];
        int frag = n >> 4;
        int s = k >> 5;
        int lane = (n & 15) | (((k >> 3) & 3) << 4);
        int elem = k & 7;
        size_t off = (((size_t)(frag * NS + s)) * 64 + lane) * 8 + elem;
        unsigned short h = f2bf(w);
        Wh[off] = (short)h;
        Wl[off] = (short)f2bf(w - bf2f(h));
    }
}

// ---------------- fused MFMA GEMM + fo-pool scan (+ mean-pool) ----------------
// Ap: bf16 plane [Mm+128][K].  Wh/Wl: frag-packed.  Hout: bf16 plane [Mm+128][H].
// POOL: pooled[b*Ss+s] = mean_c h[s][c] instead of Hout.
// Grid: Bb*NCK blocks, 512 threads (8 waves). Per block: chunk of 256 steps + 64 warmup,
// processed in 64-row sub-tiles: stage A -> MFMA (2-term bf16 split) -> zf to LDS -> scan.
template <int K, int H, bool POOL>
__global__ __launch_bounds__(512) void qrnn_fused(const short* __restrict__ Ap,
                                                  const short* __restrict__ Wh,
                                                  const short* __restrict__ Wl,
                                                  const float* __restrict__ bias,
                                                  short* __restrict__ Hout,
                                                  float* __restrict__ pooled) {
    constexpr int NS = K / 32;                    // k-steps
    constexpr int WN = (H / 16 < 8) ? (H / 16) : 8;  // col wave-groups
    constexpr int WR = 8 / WN;                    // row wave-groups
    constexpr int NZF = H / (16 * WN);            // z col-frags per wave
    constexpr int RPW = 64 / WR;                  // rows per wave
    constexpr int RF = RPW / 16;                  // row frags per wave
    constexpr int LDA = K + 8;                    // padded LDS stride (halves)

    __shared__ short As[64 * LDA];
    __shared__ unsigned zfs[64][H + 1];

    const int tid = threadIdx.x;
    const int lane = tid & 63;
    const int w = tid >> 6;
    const int rg = w / WN, cg = w % WN;
    const int l15 = lane & 15, lh = lane >> 4;

    const int bi = blockIdx.x;
    const int b = bi / NCK, ck = bi % NCK;
    const int s0 = ck * 256;

    float hscan = 0.f;                            // per scan-thread fo-pool state

    const int tstart = (ck == 0) ? 0 : -1;
    for (int t = tstart; t < 4; ++t) {
        const int st = s0 + t * 64;               // sub-tile start (sequence-local)
        if (st >= Ss) break;
        const size_t grow0 = (size_t)b * Ss + st;

        // ---- stage A sub-tile (coalesced 16B, padded LDS rows) ----
        {
            constexpr int CH = K / 8;
            for (int q = tid; q < 64 * CH; q += 512) {
                int r = q / CH, hq = q % CH;
                *(bs8*)&As[r * LDA + hq * 8] = *(const bs8*)&Ap[(grow0 + r) * K + hq * 8];
            }
        }
        __syncthreads();

        // ---- MFMA: wave (rg,cg) owns RPW rows x (NZF z + NZF f) col-frags ----
        f32x4 acc[RF][2 * NZF];
#pragma unroll
        for (int i = 0; i < RF; ++i)
#pragma unroll
            for (int j = 0; j < 2 * NZF; ++j) acc[i][j] = (f32x4)0.f;

#pragma unroll
        for (int s = 0; s < NS; ++s) {
            bs8 ah[RF];
#pragma unroll
            for (int i = 0; i < RF; ++i)
                ah[i] = *(const bs8*)&As[(rg * RPW + i * 16 + l15) * LDA + s * 32 + lh * 8];
#pragma unroll
            for (int nz = 0; nz < NZF; ++nz) {
                int fz = cg * NZF + nz;
                int ff = H / 16 + fz;
                bs8 bzh = *(const bs8*)&Wh[(((size_t)fz * NS + s) * 64 + lane) * 8];
                bs8 bzl = *(const bs8*)&Wl[(((size_t)fz * NS + s) * 64 + lane) * 8];
                bs8 bfh = *(const bs8*)&Wh[(((size_t)ff * NS + s) * 64 + lane) * 8];
                bs8 bfl = *(const bs8*)&Wl[(((size_t)ff * NS + s) * 64 + lane) * 8];
#pragma unroll
                for (int i = 0; i < RF; ++i) {
                    acc[i][nz] = __builtin_amdgcn_mfma_f32_16x16x32_bf16(ah[i], bzh, acc[i][nz], 0, 0, 0);
                    acc[i][nz] = __builtin_amdgcn_mfma_f32_16x16x32_bf16(ah[i], bzl, acc[i][nz], 0, 0, 0);
                    acc[i][NZF + nz] = __builtin_amdgcn_mfma_f32_16x16x32_bf16(ah[i], bfh, acc[i][NZF + nz], 0, 0, 0);
                    acc[i][NZF + nz] = __builtin_amdgcn_mfma_f32_16x16x32_bf16(ah[i], bfl, acc[i][NZF + nz], 0, 0, 0);
                }
            }
        }

        // ---- epilogue: bias + activations, pack (z,f) -> zfs ----
#pragma unroll
        for (int nz = 0; nz < NZF; ++nz) {
            int c = cg * (16 * NZF) + nz * 16 + l15;
            float bz = bias[c], bfv = bias[H + c];
#pragma unroll
            for (int i = 0; i < RF; ++i) {
                int rbase = rg * RPW + i * 16 + lh * 4;
#pragma unroll
                for (int r = 0; r < 4; ++r) {
                    float zv = fast_tanh(acc[i][nz][r] + bz);
                    float fv = fast_sigmoid(acc[i][NZF + nz][r] + bfv);
                    zfs[rbase + r][c] = (((unsigned)f2bf(zv)) << 16) | (unsigned)f2bf(fv);
                }
            }
        }
        __syncthreads();

        // ---- fo-pool scan over the 64 rows (thread c owns channel c) ----
        if (tid < H) {
            int c = tid;
            float h = hscan;
#pragma unroll 8
            for (int r = 0; r < 64; ++r) {
                unsigned u = zfs[r][c];
                float z = bf2f((unsigned short)(u >> 16));
                float f = bf2f((unsigned short)(u & 0xFFFF));
                h = fmaf(f, h - z, z);
                if (POOL) {
                    zfs[r][c] = __float_as_uint(h);
                } else {
                    int s = st + r;
                    if (t >= 0 && s < Ss)
                        Hout[((size_t)b * Ss + s) * H + c] = (short)f2bf(h);
                }
            }
            hscan = h;
        }
        __syncthreads();

        if (POOL) {
            if (t >= 0) {
                // 8 waves x 8 rows: shuffle-reduce 256 channels -> pooled
#pragma unroll
                for (int rr = 0; rr < 8; ++rr) {
                    int r = w * 8 + rr;
                    float sum = __uint_as_float(zfs[r][lane]) +
                                __uint_as_float(zfs[r][lane + 64]) +
                                __uint_as_float(zfs[r][lane + 128]) +
                                __uint_as_float(zfs[r][lane + 192]);
#pragma unroll
                    for (int off = 32; off >= 1; off >>= 1)
                        sum += __shfl_xor(sum, off, 64);
                    int s = st + r;
                    if (lane == 0 && s < Ss)
                        pooled[(size_t)b * Ss + s] = sum * (1.f / 256.f);
                }
            }
            __syncthreads();
        }
    }
}

// ---------------- small fp32 GEMM (layers with K<32) ----------------
template <int K>
__global__ __launch_bounds__(256) void qrnn_gemm(const float* __restrict__ A,
                                                 const float* __restrict__ W,
                                                 const float* __restrict__ bias,
                                                 float* __restrict__ ZF,
                                                 int Nfull, int Wout, int Hg, int z0, int f0) {
    constexpr int BM = 64, BN = 64;
    constexpr int BK = (K < 32) ? K : 32;
    __shared__ float As[BK][BM + 4];
    __shared__ float Bs[BK][BN];
    const int tid = threadIdx.x;
    const int tx = tid % 16, ty = tid / 16;
    const int m0 = blockIdx.x * BM;
    const int n0 = blockIdx.y * BN;
    float acc[4][4] = {};

    for (int k0 = 0; k0 < K; k0 += BK) {
        constexpr int KQ = BK / 4;
        constexpr int AV = BM * KQ;
        for (int v = tid; v < AV; v += 256) {
            int m = v / KQ, kq = v % KQ;
            float4 av = *(const float4*)&A[(size_t)(m0 + m) * K + k0 + kq * 4];
            As[kq * 4 + 0][m] = av.x;
            As[kq * 4 + 1][m] = av.y;
            As[kq * 4 + 2][m] = av.z;
            As[kq * 4 + 3][m] = av.w;
        }
        constexpr int BV = BK * 16;
        for (int v = tid; v < BV; v += 256) {
            int ki = v / 16, nq = v % 16;
            int j = n0 + nq * 4;
            float4 bv = make_float4(0.f, 0.f, 0.f, 0.f);
            if (j < Wout) {
                int wc = (j < Hg) ? (z0 + j) : (f0 + (j - Hg));
                bv = *(const float4*)&W[(size_t)(k0 + ki) * Nfull + wc];
            }
            *(float4*)&Bs[ki][nq * 4] = bv;
        }
        __syncthreads();
#pragma unroll
        for (int kk = 0; kk < BK; ++kk) {
            float a[4];
#pragma unroll
            for (int i = 0; i < 4; ++i) a[i] = As[kk][ty * 4 + i];
            float4 bv = *(const float4*)&Bs[kk][tx * 4];
            float bb[4] = {bv.x, bv.y, bv.z, bv.w};
#pragma unroll
            for (int i = 0; i < 4; ++i)
#pragma unroll
                for (int j = 0; j < 4; ++j) acc[i][j] = fmaf(a[i], bb[j], acc[i][j]);
        }
        __syncthreads();
    }
    int jb = n0 + tx * 4;
    if (jb < Wout) {
        bool isz = jb < Hg;
#pragma unroll
        for (int i = 0; i < 4; ++i) {
            int gm = m0 + ty * 4 + i;
            float o[4];
#pragma unroll
            for (int jj = 0; jj < 4; ++jj) {
                int j = jb + jj;
                int wc = isz ? (z0 + j) : (f0 + (j - Hg));
                float v = acc[i][jj] + bias[wc];
                o[jj] = isz ? fast_tanh(v) : fast_sigmoid(v);
            }
            *(float4*)&ZF[(size_t)gm * Wout + jb] = make_float4(o[0], o[1], o[2], o[3]);
        }
    }
}

// ---------------- scans for small layers ----------------
// fp32 zf -> fp32 compact h (after layer0)
__global__ void scan_f2c(const float* __restrict__ zf, float* __restrict__ hout,
                         int Hg, int W2, int Hfull, int ch0) {
    int id = blockIdx.x * blockDim.x + threadIdx.x;
    int total = Bb * NCH * Hg;
    if (id >= total) return;
    int c = id % Hg;
    int p = id / Hg;
    int b = p / NCH, ck = p % NCH;
    int sc = ck * CLEN;
    float h = 0.f;
    if (ck) {
#pragma unroll 4
        for (int s = sc - WARM; s < sc; ++s) {
            size_t base = (size_t)(b * Ss + s) * W2;
            float z = zf[base + c], f = zf[base + Hg + c];
            h = fmaf(f, h - z, z);
        }
    }
#pragma unroll 5
    for (int s = sc; s < sc + CLEN; ++s) {
        size_t base = (size_t)(b * Ss + s) * W2;
        float z = zf[base + c], f = zf[base + Hg + c];
        h = fmaf(f, h - z, z);
        hout[(size_t)(b * Ss + s) * Hfull + ch0 + c] = h;
    }
}

// fp32 zf -> bf16 plane (after layer1)
__global__ void scan_f2p(const float* __restrict__ zf, short* __restrict__ Ahp,
                         int Hg, int W2, int Kn, int ch0) {
    int id = blockIdx.x * blockDim.x + threadIdx.x;
    int total = Bb * NCH * Hg;
    if (id >= total) return;
    int c = id % Hg;
    int p = id / Hg;
    int b = p / NCH, ck = p % NCH;
    int sc = ck * CLEN;
    float h = 0.f;
    if (ck) {
#pragma unroll 4
        for (int s = sc - WARM; s < sc; ++s) {
            size_t base = (size_t)(b * Ss + s) * W2;
            float z = zf[base + c], f = zf[base + Hg + c];
            h = fmaf(f, h - z, z);
        }
    }
#pragma unroll 5
    for (int s = sc; s < sc + CLEN; ++s) {
        size_t base = (size_t)(b * Ss + s) * W2;
        float z = zf[base + c], f = zf[base + Hg + c];
        h = fmaf(f, h - z, z);
        Ahp[(size_t)(b * Ss + s) * Kn + ch0 + c] = (short)f2bf(h);
    }
}

// ---------------- MLP ----------------
__global__ __launch_bounds__(256) void mlp1_kernel(const float* __restrict__ xp,
                                                   const float* __restrict__ w1,
                                                   float* __restrict__ parts) {
    const int n0 = blockIdx.x * 64;
    const int ks = blockIdx.y;
    const int kbeg = ks * 250;
    const int nl = threadIdx.x % 64, mg = threadIdx.x / 64;
    __shared__ float xs[50][68];
    float acc[16] = {};
    for (int kc = 0; kc < 5; ++kc) {
        int k0 = kbeg + kc * 50;
        __syncthreads();
        for (int idx = threadIdx.x; idx < 64 * 50; idx += 256) {
            int r = idx / 50, cc = idx % 50;
            xs[cc][r] = xp[r * Ss + k0 + cc];
        }
        __syncthreads();
#pragma unroll 5
        for (int kk = 0; kk < 50; ++kk) {
            float wv = w1[(size_t)(k0 + kk) * 1024 + n0 + nl];
#pragma unroll
            for (int q = 0; q < 4; ++q) {
                float4 xv = *(const float4*)&xs[kk][mg * 16 + q * 4];
                acc[q * 4 + 0] = fmaf(xv.x, wv, acc[q * 4 + 0]);
                acc[q * 4 + 1] = fmaf(xv.y, wv, acc[q * 4 + 1]);
                acc[q * 4 + 2] = fmaf(xv.z, wv, acc[q * 4 + 2]);
                acc[q * 4 + 3] = fmaf(xv.w, wv, acc[q * 4 + 3]);
            }
        }
    }
#pragma unroll
    for (int i = 0; i < 16; ++i) {
        int m = mg * 16 + i;
        parts[((size_t)ks * 64 + m) * 1024 + n0 + nl] = acc[i];
    }
}

__global__ void mlp1_reduce(const float* __restrict__ parts, const float* __restrict__ b1,
                            float* __restrict__ h1) {
    int id = blockIdx.x * 256 + threadIdx.x;
    int n = id % 1024, m = id / 1024;
    float s = b1[n];
#pragma unroll
    for (int ks = 0; ks < 12; ++ks) s += parts[((size_t)ks * 64 + m) * 1024 + n];
    h1[id] = fmaxf(s, 0.f);
}

__global__ void mlp2_kernel(const float* __restrict__ h1, const float* __restrict__ w2,
                            const float* __restrict__ b2, float* __restrict__ h2) {
    int m = blockIdx.x, n = threadIdx.x;
    float acc = 0.f;
#pragma unroll 8
    for (int k = 0; k < 1024; ++k) acc = fmaf(h1[m * 1024 + k], w2[k * 128 + n], acc);
    h2[m * 128 + n] = fmaxf(acc + b2[n], 0.f);
}

__global__ void mlp3_kernel(const float* __restrict__ h2, const float* __restrict__ w3,
                            const float* __restrict__ b3, float* __restrict__ out) {
    int t = threadIdx.x;
    if (t >= 640) return;
    int m = t / 10, n = t % 10;
    float acc = 0.f;
#pragma unroll
    for (int k = 0; k < 128; ++k) acc = fmaf(h2[m * 128 + k], w3[k * 10 + n], acc);
    out[t] = fmaxf(acc + b3[n], 0.f);
}

// ---------------- launcher ----------------
extern "C" void kernel_launch(void* const* d_in, const int* in_sizes, int n_in,
                              void* d_out, int out_size, void* d_ws, size_t ws_size,
                              hipStream_t stream) {
    const float* x   = (const float*)d_in[0];
    const float* wih = (const float*)d_in[1];
    const float* whh = (const float*)d_in[2];
    const float* bih = (const float*)d_in[3];
    const float* bhh = (const float*)d_in[4];
    const float* qw[5] = {(const float*)d_in[5], (const float*)d_in[7], (const float*)d_in[9],
                          (const float*)d_in[11], (const float*)d_in[13]};
    const float* qb[5] = {(const float*)d_in[6], (const float*)d_in[8], (const float*)d_in[10],
                          (const float*)d_in[12], (const float*)d_in[14]};
    const float* w1 = (const float*)d_in[15];
    const float* b1 = (const float*)d_in[16];
    const float* w2 = (const float*)d_in[17];
    const float* b2 = (const float*)d_in[18];
    const float* w3 = (const float*)d_in[19];
    const float* b3 = (const float*)d_in[20];
    float* out = (float*)d_out;

    // ---- ws carve ----
    char* ws = (char*)d_ws;
    size_t off = 0;
    auto carve = [&](size_t sz) {
        char* q = ws + off;
        off += (sz + 255) & ~size_t(255);
        return q;
    };
    float* h4    = (float*)carve((size_t)Mm * 4 * 4);              // RNN out
    float* h16   = (float*)carve((size_t)Mm * 16 * 4);             // L0 out (fp32)
    float* zf32  = (float*)carve((size_t)Mm * 64 * 4);             // L0/L1 zf buffer
    short* p32   = (short*)carve((size_t)(Mm + 128) * 32 * 2);     // L1 out plane
    short* p64   = (short*)carve((size_t)(Mm + 128) * 64 * 2);     // L2 out plane
    short* p128  = (short*)carve((size_t)(Mm + 128) * 128 * 2);    // L3 out plane
    float* pooled = (float*)carve((size_t)Bb * Ss * 4);
    float* parts  = (float*)carve(12ull * 64 * 1024 * 4);
    float* h1m    = (float*)carve(64ull * 1024 * 4);
    float* h2m    = (float*)carve(64ull * 128 * 4);
    short* wh2 = (short*)carve(4096 * 2);
    short* wl2 = (short*)carve(4096 * 2);
    short* wh3 = (short*)carve(16384 * 2);
    short* wl3 = (short*)carve(16384 * 2);
    short* wh4 = (short*)carve(65536 * 2);
    short* wl4 = (short*)carve(65536 * 2);
    (void)ws_size;

    // ---- weight prep (frag-packed bf16 hi/lo) ----
    prep_wfrag<<<8,  256, 0, stream>>>(qw[2], wh2, wl2, 32, 128);
    prep_wfrag<<<16, 256, 0, stream>>>(qw[3], wh3, wl3, 64, 256);
    prep_wfrag<<<64, 256, 0, stream>>>(qw[4], wh4, wl4, 128, 512);

    // ---- RNN ----
    rnn_kernel2<<<Bb, 64, 0, stream>>>(x, wih, whh, bih, bhh, h4);

    // ---- layer0 (K=4, H=16): fp32 gemm + scan -> h16 ----
    {
        dim3 grid(Mm / 64, 1);
        qrnn_gemm<4><<<grid, 256, 0, stream>>>(h4, qw[0], qb[0], zf32, 32, 32, 16, 0, 16);
        int total = Bb * NCH * 16;
        scan_f2c<<<(total + 255) / 256, 256, 0, stream>>>(zf32, h16, 16, 32, 16, 0);
    }
    // ---- layer1 (K=16, H=32): fp32 gemm + scan -> bf16 plane p32 ----
    {
        dim3 grid(Mm / 64, 1);
        qrnn_gemm<16><<<grid, 256, 0, stream>>>(h16, qw[1], qb[1], zf32, 64, 64, 32, 0, 32);
        int total = Bb * NCH * 32;
        scan_f2p<<<(total + 255) / 256, 256, 0, stream>>>(zf32, p32, 32, 64, 32, 0);
    }
    // ---- fused layers 2..4 ----
    qrnn_fused<32, 64, false><<<Bb * NCK, 512, 0, stream>>>(p32, wh2, wl2, qb[2], p64, nullptr);
    qrnn_fused<64, 128, false><<<Bb * NCK, 512, 0, stream>>>(p64, wh3, wl3, qb[3], p128, nullptr);
    qrnn_fused<128, 256, true><<<Bb * NCK, 512, 0, stream>>>(p128, wh4, wl4, qb[4], nullptr, pooled);

    // ---- MLP ----
    mlp1_kernel<<<dim3(16, 12), 256, 0, stream>>>(pooled, w1, parts);
    mlp1_reduce<<<256, 256, 0, stream>>>(parts, b1, h1m);
    mlp2_kernel<<<64, 128, 0, stream>>>(h1m, w2, b2, h2m);
    mlp3_kernel<<<1, 640, 0, stream>>>(h2m, w3, b3, out);
    (void)in_sizes; (void)n_in; (void)out_size;
}

// Round 10
// 598.387 us; speedup vs baseline: 2.3552x; 1.0300x over previous
//
#include <hip/hip_runtime.h>

#define DEVI __device__ __forceinline__

static constexpr int Bb = 64;
static constexpr int Ss = 3000;
static constexpr int Mm = Bb * Ss;      // 192000
static constexpr int NCH = 12;          // sequence chunks (L0/L1 scans)
static constexpr int CLEN = 250;        // chunk length (L0/L1 scans)
static constexpr int WARM = 64;         // scan warmup steps
static constexpr int NCK = 12;          // fused chunks (256 steps each)
static constexpr int RCH = 60;          // rnn chunks
static constexpr int RCLEN = 50;        // rnn chunk length
static constexpr int RWARM = 32;        // rnn warmup steps

typedef short bs8 __attribute__((ext_vector_type(8)));
typedef float f32x4 __attribute__((ext_vector_type(4)));

// fast activations: v_exp + v_rcp (1-ulp rcp; fine vs bf16 storage)
DEVI float fast_tanh(float x) {
    float e = __expf(2.0f * x);
    return 1.0f - 2.0f * __builtin_amdgcn_rcpf(e + 1.0f);
}
DEVI float fast_sigmoid(float x) {
    return __builtin_amdgcn_rcpf(1.0f + __expf(-x));
}
DEVI unsigned short f2bf(float f) {
    unsigned u = __float_as_uint(f);
    u += 0x7FFF + ((u >> 16) & 1);
    return (unsigned short)(u >> 16);
}
DEVI float bf2f(unsigned short h) { return __uint_as_float(((unsigned)h) << 16); }

// ---------------- RNN (hidden=4): LDS-staged x, 60 chunks/batch ----------------
__global__ __launch_bounds__(64) void rnn_kernel2(const float* __restrict__ x,
                                                  const float* __restrict__ wih,
                                                  const float* __restrict__ whh,
                                                  const float* __restrict__ bih,
                                                  const float* __restrict__ bhh,
                                                  float* __restrict__ hout) {
    __shared__ float xs[Ss];
    int b = blockIdx.x;
    for (int i = threadIdx.x; i < Ss / 4; i += 64) {
        *(float4*)&xs[i * 4] = *(const float4*)&x[b * Ss + i * 4];
    }
    __syncthreads();
    int ck = threadIdx.x;
    if (ck >= RCH) return;
    float w[4][4], wi[4], bc[4];
#pragma unroll
    for (int j = 0; j < 4; ++j) {
        wi[j] = wih[j];
        bc[j] = bih[j] + bhh[j];
#pragma unroll
        for (int i = 0; i < 4; ++i) w[j][i] = whh[j * 4 + i];
    }
    float h0 = 0.f, h1 = 0.f, h2 = 0.f, h3 = 0.f;
    int sc = ck * RCLEN;
    int sb = ck ? (sc - RWARM) : 0;
#pragma unroll 4
    for (int s = sb; s < sc; ++s) {
        float xv = xs[s];
        float n0 = fast_tanh(fmaf(xv, wi[0], bc[0]) + w[0][0]*h0 + w[0][1]*h1 + w[0][2]*h2 + w[0][3]*h3);
        float n1 = fast_tanh(fmaf(xv, wi[1], bc[1]) + w[1][0]*h0 + w[1][1]*h1 + w[1][2]*h2 + w[1][3]*h3);
        float n2 = fast_tanh(fmaf(xv, wi[2], bc[2]) + w[2][0]*h0 + w[2][1]*h1 + w[2][2]*h2 + w[2][3]*h3);
        float n3 = fast_tanh(fmaf(xv, wi[3], bc[3]) + w[3][0]*h0 + w[3][1]*h1 + w[3][2]*h2 + w[3][3]*h3);
        h0 = n0; h1 = n1; h2 = n2; h3 = n3;
    }
#pragma unroll 5
    for (int s = sc; s < sc + RCLEN; ++s) {
        float xv = xs[s];
        float n0 = fast_tanh(fmaf(xv, wi[0], bc[0]) + w[0][0]*h0 + w[0][1]*h1 + w[0][2]*h2 + w[0][3]*h3);
        float n1 = fast_tanh(fmaf(xv, wi[1], bc[1]) + w[1][0]*h0 + w[1][1]*h1 + w[1][2]*h2 + w[1][3]*h3);
        float n2 = fast_tanh(fmaf(xv, wi[2], bc[2]) + w[2][0]*h0 + w[2][1]*h1 + w[2][2]*h2 + w[2][3]*h3);
        float n3 = fast_tanh(fmaf(xv, wi[3], bc[3]) + w[3][0]*h0 + w[3][1]*h1 + w[3][2]*h2 + w[3][3]*h3);
        h0 = n0; h1 = n1; h2 = n2; h3 = n3;
        *(float4*)&hout[(size_t)(b * Ss + s) * 4] = make_float4(h0, h1, h2, h3);
    }
}

// -------- weight prep: W (K,2H) fp32 -> frag-packed bf16 hi/lo planes --------
// Layout: [frag=n/16][s=k/32][lane=(n&15)|(((k>>3)&3)<<4)][elem=k&7]
__global__ void prep_wfrag(const float* __restrict__ W, short* __restrict__ Wh,
                           short* __restrict__ Wl, int K, int N2) {
    int total = K * N2;
    int NS = K / 32;
    for (int t = blockIdx.x * blockDim.x + threadIdx.x; t < total; t += gridDim.x * blockDim.x) {
        int n = t / K, k = t % K;
        float w = W[(size_t)k * N2 + n];
        int frag = n >> 4;
        int s = k >> 5;
        int lane = (n & 15) | (((k >> 3) & 3) << 4);
        int elem = k & 7;
        size_t off = (((size_t)(frag * NS + s)) * 64 + lane) * 8 + elem;
        unsigned short h = f2bf(w);
        Wh[off] = (short)h;
        Wl[off] = (short)f2bf(w - bf2f(h));
    }
}

// ---------------- fused MFMA GEMM + fo-pool scan (+ mean-pool) ----------------
// Ap: bf16 plane [Mm+128][K].  Wh/Wl: frag-packed.  Hout: bf16 plane [Mm+128][H].
// 32-row sub-tiles (LDS ~42KB at K=128/H=256 -> 3 blocks/CU; grid 768 = fully resident,
// so other blocks' MFMA overlaps this block's scan/barrier phases).
// zfs stride H+4: 4-row lh-group epilogue writes land 16 banks apart -> <=2-way (free).
template <int K, int H, bool POOL>
__global__ __launch_bounds__(512) void qrnn_fused(const short* __restrict__ Ap,
                                                  const short* __restrict__ Wh,
                                                  const short* __restrict__ Wl,
                                                  const float* __restrict__ bias,
                                                  short* __restrict__ Hout,
                                                  float* __restrict__ pooled) {
    constexpr int SUBR = 32;                      // rows per sub-tile
    constexpr int NS = K / 32;                    // k-steps
    constexpr int WN = (H / 16 < 8) ? (H / 16) : 8;  // col wave-groups
    constexpr int WR = 8 / WN;                    // row wave-groups
    constexpr int NZF = H / (16 * WN);            // z col-frags per wave
    constexpr int RPW = SUBR / WR;                // rows per wave
    constexpr int RF = RPW / 16;                  // row frags per wave
    constexpr int LDA = K + 8;                    // padded LDS stride (halves)
    constexpr int ZP = H + 4;                     // zfs stride (words)

    __shared__ short As[SUBR * LDA];
    __shared__ unsigned zfs[SUBR][ZP];

    const int tid = threadIdx.x;
    const int lane = tid & 63;
    const int w = tid >> 6;
    const int rg = w / WN, cg = w % WN;
    const int l15 = lane & 15, lh = lane >> 4;

    const int bi = blockIdx.x;
    const int b = bi / NCK, ck = bi % NCK;
    const int s0 = ck * 256;

    float hscan = 0.f;                            // per scan-thread fo-pool state

    const int tstart = (ck == 0) ? 0 : -2;        // 2 warmup sub-tiles = 64 steps
    for (int t = tstart; t < 8; ++t) {
        const int st = s0 + t * SUBR;             // sub-tile start
        if (st >= Ss) break;
        const size_t grow0 = (size_t)b * Ss + st;

        // ---- stage A sub-tile (coalesced 16B, padded LDS rows) ----
        {
            constexpr int CH = K / 8;
            for (int q = tid; q < SUBR * CH; q += 512) {
                int r = q / CH, hq = q % CH;
                *(bs8*)&As[r * LDA + hq * 8] = *(const bs8*)&Ap[(grow0 + r) * K + hq * 8];
            }
        }
        __syncthreads();

        // ---- MFMA: wave (rg,cg) owns RPW rows x (NZF z + NZF f) col-frags ----
        f32x4 acc[RF][2 * NZF];
#pragma unroll
        for (int i = 0; i < RF; ++i)
#pragma unroll
            for (int j = 0; j < 2 * NZF; ++j) acc[i][j] = (f32x4)0.f;

#pragma unroll
        for (int s = 0; s < NS; ++s) {
            bs8 ah[RF];
#pragma unroll
            for (int i = 0; i < RF; ++i)
                ah[i] = *(const bs8*)&As[(rg * RPW + i * 16 + l15) * LDA + s * 32 + lh * 8];
#pragma unroll
            for (int nz = 0; nz < NZF; ++nz) {
                int fz = cg * NZF + nz;
                int ff = H / 16 + fz;
                bs8 bzh = *(const bs8*)&Wh[(((size_t)fz * NS + s) * 64 + lane) * 8];
                bs8 bzl = *(const bs8*)&Wl[(((size_t)fz * NS + s) * 64 + lane) * 8];
                bs8 bfh = *(const bs8*)&Wh[(((size_t)ff * NS + s) * 64 + lane) * 8];
                bs8 bfl = *(const bs8*)&Wl[(((size_t)ff * NS + s) * 64 + lane) * 8];
#pragma unroll
                for (int i = 0; i < RF; ++i) {
                    acc[i][nz] = __builtin_amdgcn_mfma_f32_16x16x32_bf16(ah[i], bzh, acc[i][nz], 0, 0, 0);
                    acc[i][nz] = __builtin_amdgcn_mfma_f32_16x16x32_bf16(ah[i], bzl, acc[i][nz], 0, 0, 0);
                    acc[i][NZF + nz] = __builtin_amdgcn_mfma_f32_16x16x32_bf16(ah[i], bfh, acc[i][NZF + nz], 0, 0, 0);
                    acc[i][NZF + nz] = __builtin_amdgcn_mfma_f32_16x16x32_bf16(ah[i], bfl, acc[i][NZF + nz], 0, 0, 0);
                }
            }
        }

        // ---- epilogue: bias + activations, pack (z,f) -> zfs ----
#pragma unroll
        for (int nz = 0; nz < NZF; ++nz) {
            int c = cg * (16 * NZF) + nz * 16 + l15;
            float bz = bias[c], bfv = bias[H + c];
#pragma unroll
            for (int i = 0; i < RF; ++i) {
                int rbase = rg * RPW + i * 16 + lh * 4;
#pragma unroll
                for (int r = 0; r < 4; ++r) {
                    float zv = fast_tanh(acc[i][nz][r] + bz);
                    float fv = fast_sigmoid(acc[i][NZF + nz][r] + bfv);
                    zfs[rbase + r][c] = (((unsigned)f2bf(zv)) << 16) | (unsigned)f2bf(fv);
                }
            }
        }
        __syncthreads();

        // ---- fo-pool scan over the SUBR rows (thread c owns channel c) ----
        if (tid < H) {
            int c = tid;
            float h = hscan;
#pragma unroll 8
            for (int r = 0; r < SUBR; ++r) {
                unsigned u = zfs[r][c];
                float z = bf2f((unsigned short)(u >> 16));
                float f = bf2f((unsigned short)(u & 0xFFFF));
                h = fmaf(f, h - z, z);
                if (POOL) {
                    zfs[r][c] = __float_as_uint(h);
                } else {
                    int s = st + r;
                    if (t >= 0 && s < Ss)
                        Hout[((size_t)b * Ss + s) * H + c] = (short)f2bf(h);
                }
            }
            hscan = h;
        }
        __syncthreads();

        if (POOL) {
            if (t >= 0) {
                // 8 waves x 4 rows: shuffle-reduce 256 channels -> pooled
#pragma unroll
                for (int rr = 0; rr < SUBR / 8; ++rr) {
                    int r = w * (SUBR / 8) + rr;
                    float sum = __uint_as_float(zfs[r][lane]) +
                                __uint_as_float(zfs[r][lane + 64]) +
                                __uint_as_float(zfs[r][lane + 128]) +
                                __uint_as_float(zfs[r][lane + 192]);
#pragma unroll
                    for (int off = 32; off >= 1; off >>= 1)
                        sum += __shfl_xor(sum, off, 64);
                    int s = st + r;
                    if (lane == 0 && s < Ss)
                        pooled[(size_t)b * Ss + s] = sum * (1.f / 256.f);
                }
            }
            __syncthreads();
        }
    }
}

// ---------------- small fp32 GEMM (layers with K<32) ----------------
template <int K>
__global__ __launch_bounds__(256) void qrnn_gemm(const float* __restrict__ A,
                                                 const float* __restrict__ W,
                                                 const float* __restrict__ bias,
                                                 float* __restrict__ ZF,
                                                 int Nfull, int Wout, int Hg, int z0, int f0) {
    constexpr int BM = 64, BN = 64;
    constexpr int BK = (K < 32) ? K : 32;
    __shared__ float As[BK][BM + 4];
    __shared__ float Bs[BK][BN];
    const int tid = threadIdx.x;
    const int tx = tid % 16, ty = tid / 16;
    const int m0 = blockIdx.x * BM;
    const int n0 = blockIdx.y * BN;
    float acc[4][4] = {};

    for (int k0 = 0; k0 < K; k0 += BK) {
        constexpr int KQ = BK / 4;
        constexpr int AV = BM * KQ;
        for (int v = tid; v < AV; v += 256) {
            int m = v / KQ, kq = v % KQ;
            float4 av = *(const float4*)&A[(size_t)(m0 + m) * K + k0 + kq * 4];
            As[kq * 4 + 0][m] = av.x;
            As[kq * 4 + 1][m] = av.y;
            As[kq * 4 + 2][m] = av.z;
            As[kq * 4 + 3][m] = av.w;
        }
        constexpr int BV = BK * 16;
        for (int v = tid; v < BV; v += 256) {
            int ki = v / 16, nq = v % 16;
            int j = n0 + nq * 4;
            float4 bv = make_float4(0.f, 0.f, 0.f, 0.f);
            if (j < Wout) {
                int wc = (j < Hg) ? (z0 + j) : (f0 + (j - Hg));
                bv = *(const float4*)&W[(size_t)(k0 + ki) * Nfull + wc];
            }
            *(float4*)&Bs[ki][nq * 4] = bv;
        }
        __syncthreads();
#pragma unroll
        for (int kk = 0; kk < BK; ++kk) {
            float a[4];
#pragma unroll
            for (int i = 0; i < 4; ++i) a[i] = As[kk][ty * 4 + i];
            float4 bv = *(const float4*)&Bs[kk][tx * 4];
            float bb[4] = {bv.x, bv.y, bv.z, bv.w};
#pragma unroll
            for (int i = 0; i < 4; ++i)
#pragma unroll
                for (int j = 0; j < 4; ++j) acc[i][j] = fmaf(a[i], bb[j], acc[i][j]);
        }
        __syncthreads();
    }
    int jb = n0 + tx * 4;
    if (jb < Wout) {
        bool isz = jb < Hg;
#pragma unroll
        for (int i = 0; i < 4; ++i) {
            int gm = m0 + ty * 4 + i;
            float o[4];
#pragma unroll
            for (int jj = 0; jj < 4; ++jj) {
                int j = jb + jj;
                int wc = isz ? (z0 + j) : (f0 + (j - Hg));
                float v = acc[i][jj] + bias[wc];
                o[jj] = isz ? fast_tanh(v) : fast_sigmoid(v);
            }
            *(float4*)&ZF[(size_t)gm * Wout + jb] = make_float4(o[0], o[1], o[2], o[3]);
        }
    }
}

// ---------------- scans for small layers ----------------
// fp32 zf -> fp32 compact h (after layer0)
__global__ void scan_f2c(const float* __restrict__ zf, float* __restrict__ hout,
                         int Hg, int W2, int Hfull, int ch0) {
    int id = blockIdx.x * blockDim.x + threadIdx.x;
    int total = Bb * NCH * Hg;
    if (id >= total) return;
    int c = id % Hg;
    int p = id / Hg;
    int b = p / NCH, ck = p % NCH;
    int sc = ck * CLEN;
    float h = 0.f;
    if (ck) {
#pragma unroll 4
        for (int s = sc - WARM; s < sc; ++s) {
            size_t base = (size_t)(b * Ss + s) * W2;
            float z = zf[base + c], f = zf[base + Hg + c];
            h = fmaf(f, h - z, z);
        }
    }
#pragma unroll 5
    for (int s = sc; s < sc + CLEN; ++s) {
        size_t base = (size_t)(b * Ss + s) * W2;
        float z = zf[base + c], f = zf[base + Hg + c];
        h = fmaf(f, h - z, z);
        hout[(size_t)(b * Ss + s) * Hfull + ch0 + c] = h;
    }
}

// fp32 zf -> bf16 plane (after layer1)
__global__ void scan_f2p(const float* __restrict__ zf, short* __restrict__ Ahp,
                         int Hg, int W2, int Kn, int ch0) {
    int id = blockIdx.x * blockDim.x + threadIdx.x;
    int total = Bb * NCH * Hg;
    if (id >= total) return;
    int c = id % Hg;
    int p = id / Hg;
    int b = p / NCH, ck = p % NCH;
    int sc = ck * CLEN;
    float h = 0.f;
    if (ck) {
#pragma unroll 4
        for (int s = sc - WARM; s < sc; ++s) {
            size_t base = (size_t)(b * Ss + s) * W2;
            float z = zf[base + c], f = zf[base + Hg + c];
            h = fmaf(f, h - z, z);
        }
    }
#pragma unroll 5
    for (int s = sc; s < sc + CLEN; ++s) {
        size_t base = (size_t)(b * Ss + s) * W2;
        float z = zf[base + c], f = zf[base + Hg + c];
        h = fmaf(f, h - z, z);
        Ahp[(size_t)(b * Ss + s) * Kn + ch0 + c] = (short)f2bf(h);
    }
}

// ---------------- MLP ----------------
__global__ __launch_bounds__(256) void mlp1_kernel(const float* __restrict__ xp,
                                                   const float* __restrict__ w1,
                                                   float* __restrict__ parts) {
    const int n0 = blockIdx.x * 64;
    const int ks = blockIdx.y;
    const int kbeg = ks * 250;
    const int nl = threadIdx.x % 64, mg = threadIdx.x / 64;
    __shared__ float xs[50][68];
    float acc[16] = {};
    for (int kc = 0; kc < 5; ++kc) {
        int k0 = kbeg + kc * 50;
        __syncthreads();
        for (int idx = threadIdx.x; idx < 64 * 50; idx += 256) {
            int r = idx / 50, cc = idx % 50;
            xs[cc][r] = xp[r * Ss + k0 + cc];
        }
        __syncthreads();
#pragma unroll 5
        for (int kk = 0; kk < 50; ++kk) {
            float wv = w1[(size_t)(k0 + kk) * 1024 + n0 + nl];
#pragma unroll
            for (int q = 0; q < 4; ++q) {
                float4 xv = *(const float4*)&xs[kk][mg * 16 + q * 4];
                acc[q * 4 + 0] = fmaf(xv.x, wv, acc[q * 4 + 0]);
                acc[q * 4 + 1] = fmaf(xv.y, wv, acc[q * 4 + 1]);
                acc[q * 4 + 2] = fmaf(xv.z, wv, acc[q * 4 + 2]);
                acc[q * 4 + 3] = fmaf(xv.w, wv, acc[q * 4 + 3]);
            }
        }
    }
#pragma unroll
    for (int i = 0; i < 16; ++i) {
        int m = mg * 16 + i;
        parts[((size_t)ks * 64 + m) * 1024 + n0 + nl] = acc[i];
    }
}

__global__ void mlp1_reduce(const float* __restrict__ parts, const float* __restrict__ b1,
                            float* __restrict__ h1) {
    int id = blockIdx.x * 256 + threadIdx.x;
    int n = id % 1024, m = id / 1024;
    float s = b1[n];
#pragma unroll
    for (int ks = 0; ks < 12; ++ks) s += parts[((size_t)ks * 64 + m) * 1024 + n];
    h1[id] = fmaxf(s, 0.f);
}

__global__ void mlp2_kernel(const float* __restrict__ h1, const float* __restrict__ w2,
                            const float* __restrict__ b2, float* __restrict__ h2) {
    int m = blockIdx.x, n = threadIdx.x;
    float acc = 0.f;
#pragma unroll 8
    for (int k = 0; k < 1024; ++k) acc = fmaf(h1[m * 1024 + k], w2[k * 128 + n], acc);
    h2[m * 128 + n] = fmaxf(acc + b2[n], 0.f);
}

__global__ void mlp3_kernel(const float* __restrict__ h2, const float* __restrict__ w3,
                            const float* __restrict__ b3, float* __restrict__ out) {
    int t = threadIdx.x;
    if (t >= 640) return;
    int m = t / 10, n = t % 10;
    float acc = 0.f;
#pragma unroll
    for (int k = 0; k < 128; ++k) acc = fmaf(h2[m * 128 + k], w3[k * 10 + n], acc);
    out[t] = fmaxf(acc + b3[n], 0.f);
}

// ---------------- launcher ----------------
extern "C" void kernel_launch(void* const* d_in, const int* in_sizes, int n_in,
                              void* d_out, int out_size, void* d_ws, size_t ws_size,
                              hipStream_t stream) {
    const float* x   = (const float*)d_in[0];
    const float* wih = (const float*)d_in[1];
    const float* whh = (const float*)d_in[2];
    const float* bih = (const float*)d_in[3];
    const float* bhh = (const float*)d_in[4];
    const float* qw[5] = {(const float*)d_in[5], (const float*)d_in[7], (const float*)d_in[9],
                          (const float*)d_in[11], (const float*)d_in[13]};
    const float* qb[5] = {(const float*)d_in[6], (const float*)d_in[8], (const float*)d_in[10],
                          (const float*)d_in[12], (const float*)d_in[14]};
    const float* w1 = (const float*)d_in[15];
    const float* b1 = (const float*)d_in[16];
    const float* w2 = (const float*)d_in[17];
    const float* b2 = (const float*)d_in[18];
    const float* w3 = (const float*)d_in[19];
    const float* b3 = (const float*)d_in[20];
    float* out = (float*)d_out;

    // ---- ws carve ----
    char* ws = (char*)d_ws;
    size_t off = 0;
    auto carve = [&](size_t sz) {
        char* q = ws + off;
        off += (sz + 255) & ~size_t(255);
        return q;
    };
    float* h4    = (float*)carve((size_t)Mm * 4 * 4);              // RNN out
    float* h16   = (float*)carve((size_t)Mm * 16 * 4);             // L0 out (fp32)
    float* zf32  = (float*)carve((size_t)Mm * 64 * 4);             // L0/L1 zf buffer
    short* p32   = (short*)carve((size_t)(Mm + 128) * 32 * 2);     // L1 out plane
    short* p64   = (short*)carve((size_t)(Mm + 128) * 64 * 2);     // L2 out plane
    short* p128  = (short*)carve((size_t)(Mm + 128) * 128 * 2);    // L3 out plane
    float* pooled = (float*)carve((size_t)Bb * Ss * 4);
    float* parts  = (float*)carve(12ull * 64 * 1024 * 4);
    float* h1m    = (float*)carve(64ull * 1024 * 4);
    float* h2m    = (float*)carve(64ull * 128 * 4);
    short* wh2 = (short*)carve(4096 * 2);
    short* wl2 = (short*)carve(4096 * 2);
    short* wh3 = (short*)carve(16384 * 2);
    short* wl3 = (short*)carve(16384 * 2);
    short* wh4 = (short*)carve(65536 * 2);
    short* wl4 = (short*)carve(65536 * 2);
    (void)ws_size;

    // ---- weight prep (frag-packed bf16 hi/lo) ----
    prep_wfrag<<<8,  256, 0, stream>>>(qw[2], wh2, wl2, 32, 128);
    prep_wfrag<<<16, 256, 0, stream>>>(qw[3], wh3, wl3, 64, 256);
    prep_wfrag<<<64, 256, 0, stream>>>(qw[4], wh4, wl4, 128, 512);

    // ---- RNN ----
    rnn_kernel2<<<Bb, 64, 0, stream>>>(x, wih, whh, bih, bhh, h4);

    // ---- layer0 (K=4, H=16): fp32 gemm + scan -> h16 ----
    {
        dim3 grid(Mm / 64, 1);
        qrnn_gemm<4><<<grid, 256, 0, stream>>>(h4, qw[0], qb[0], zf32, 32, 32, 16, 0, 16);
        int total = Bb * NCH * 16;
        scan_f2c<<<(total + 255) / 256, 256, 0, stream>>>(zf32, h16, 16, 32, 16, 0);
    }
    // ---- layer1 (K=16, H=32): fp32 gemm + scan -> bf16 plane p32 ----
    {
        dim3 grid(Mm / 64, 1);
        qrnn_gemm<16><<<grid, 256, 0, stream>>>(h16, qw[1], qb[1], zf32, 64, 64, 32, 0, 32);
        int total = Bb * NCH * 32;
        scan_f2p<<<(total + 255) / 256, 256, 0, stream>>>(zf32, p32, 32, 64, 32, 0);
    }
    // ---- fused layers 2..4 ----
    qrnn_fused<32, 64, false><<<Bb * NCK, 512, 0, stream>>>(p32, wh2, wl2, qb[2], p64, nullptr);
    qrnn_fused<64, 128, false><<<Bb * NCK, 512, 0, stream>>>(p64, wh3, wl3, qb[3], p128, nullptr);
    qrnn_fused<128, 256, true><<<Bb * NCK, 512, 0, stream>>>(p128, wh4, wl4, qb[4], nullptr, pooled);

    // ---- MLP ----
    mlp1_kernel<<<dim3(16, 12), 256, 0, stream>>>(pooled, w1, parts);
    mlp1_reduce<<<256, 256, 0, stream>>>(parts, b1, h1m);
    mlp2_kernel<<<64, 128, 0, stream>>>(h1m, w2, b2, h2m);
    mlp3_kernel<<<1, 640, 0, stream>>>(h2m, w3, b3, out);
    (void)in_sizes; (void)n_in; (void)out_size;
}

// Round 11
// 552.429 us; speedup vs baseline: 2.5512x; 1.0832x over previous
//
#include <hip/hip_runtime.h>

#define DEVI __device__ __forceinline__

static constexpr int Bb = 64;
static constexpr int Ss = 3000;
static constexpr int Mm = Bb * Ss;      // 192000
static constexpr int NCH = 12;          // sequence chunks (L0/L1 scans)
static constexpr int CLEN = 250;        // chunk length (L0/L1 scans)
static constexpr int WARM = 64;         // scan warmup steps
static constexpr int NCK = 12;          // fused chunks (256 steps each)
static constexpr int RCH = 60;          // rnn chunks
static constexpr int RCLEN = 50;        // rnn chunk length
static constexpr int RWARM = 32;        // rnn warmup steps

typedef short bs8 __attribute__((ext_vector_type(8)));
typedef float f32x4 __attribute__((ext_vector_type(4)));

// fast activations: v_exp + v_rcp (1-ulp rcp; fine vs bf16 storage)
DEVI float fast_tanh(float x) {
    float e = __expf(2.0f * x);
    return 1.0f - 2.0f * __builtin_amdgcn_rcpf(e + 1.0f);
}
DEVI float fast_sigmoid(float x) {
    return __builtin_amdgcn_rcpf(1.0f + __expf(-x));
}
DEVI unsigned short f2bf(float f) {
    unsigned u = __float_as_uint(f);
    u += 0x7FFF + ((u >> 16) & 1);
    return (unsigned short)(u >> 16);
}
DEVI float bf2f(unsigned short h) { return __uint_as_float(((unsigned)h) << 16); }

// ---------------- RNN (hidden=4): LDS-staged x, 60 chunks/batch ----------------
__global__ __launch_bounds__(64) void rnn_kernel2(const float* __restrict__ x,
                                                  const float* __restrict__ wih,
                                                  const float* __restrict__ whh,
                                                  const float* __restrict__ bih,
                                                  const float* __restrict__ bhh,
                                                  float* __restrict__ hout) {
    __shared__ float xs[Ss];
    int b = blockIdx.x;
    for (int i = threadIdx.x; i < Ss / 4; i += 64) {
        *(float4*)&xs[i * 4] = *(const float4*)&x[b * Ss + i * 4];
    }
    __syncthreads();
    int ck = threadIdx.x;
    if (ck >= RCH) return;
    float w[4][4], wi[4], bc[4];
#pragma unroll
    for (int j = 0; j < 4; ++j) {
        wi[j] = wih[j];
        bc[j] = bih[j] + bhh[j];
#pragma unroll
        for (int i = 0; i < 4; ++i) w[j][i] = whh[j * 4 + i];
    }
    float h0 = 0.f, h1 = 0.f, h2 = 0.f, h3 = 0.f;
    int sc = ck * RCLEN;
    int sb = ck ? (sc - RWARM) : 0;
#pragma unroll 4
    for (int s = sb; s < sc; ++s) {
        float xv = xs[s];
        float n0 = fast_tanh(fmaf(xv, wi[0], bc[0]) + w[0][0]*h0 + w[0][1]*h1 + w[0][2]*h2 + w[0][3]*h3);
        float n1 = fast_tanh(fmaf(xv, wi[1], bc[1]) + w[1][0]*h0 + w[1][1]*h1 + w[1][2]*h2 + w[1][3]*h3);
        float n2 = fast_tanh(fmaf(xv, wi[2], bc[2]) + w[2][0]*h0 + w[2][1]*h1 + w[2][2]*h2 + w[2][3]*h3);
        float n3 = fast_tanh(fmaf(xv, wi[3], bc[3]) + w[3][0]*h0 + w[3][1]*h1 + w[3][2]*h2 + w[3][3]*h3);
        h0 = n0; h1 = n1; h2 = n2; h3 = n3;
    }
#pragma unroll 5
    for (int s = sc; s < sc + RCLEN; ++s) {
        float xv = xs[s];
        float n0 = fast_tanh(fmaf(xv, wi[0], bc[0]) + w[0][0]*h0 + w[0][1]*h1 + w[0][2]*h2 + w[0][3]*h3);
        float n1 = fast_tanh(fmaf(xv, wi[1], bc[1]) + w[1][0]*h0 + w[1][1]*h1 + w[1][2]*h2 + w[1][3]*h3);
        float n2 = fast_tanh(fmaf(xv, wi[2], bc[2]) + w[2][0]*h0 + w[2][1]*h1 + w[2][2]*h2 + w[2][3]*h3);
        float n3 = fast_tanh(fmaf(xv, wi[3], bc[3]) + w[3][0]*h0 + w[3][1]*h1 + w[3][2]*h2 + w[3][3]*h3);
        h0 = n0; h1 = n1; h2 = n2; h3 = n3;
        *(float4*)&hout[(size_t)(b * Ss + s) * 4] = make_float4(h0, h1, h2, h3);
    }
}

// -------- weight prep: W (K,2H) fp32 -> frag-packed bf16 hi/lo planes --------
// Layout: [frag=n/16][s=k/32][lane=(n&15)|(((k>>3)&3)<<4)][elem=k&7]
__global__ void prep_wfrag(const float* __restrict__ W, short* __restrict__ Wh,
                           short* __restrict__ Wl, int K, int N2) {
    int total = K * N2;
    int NS = K / 32;
    for (int t = blockIdx.x * blockDim.x + threadIdx.x; t < total; t += gridDim.x * blockDim.x) {
        int n = t / K, k = t % K;
        float w = W[(size_t)k * N2 + n];
        int frag = n >> 4;
        int s = k >> 5;
        int lane = (n & 15) | (((k >> 3) & 3) << 4);
        int elem = k & 7;
        size_t off = (((size_t)(frag * NS + s)) * 64 + lane) * 8 + elem;
        unsigned short h = f2bf(w);
        Wh[off] = (short)h;
        Wl[off] = (short)f2bf(w - bf2f(h));
    }
}

// ---------------- fused MFMA GEMM + fo-pool scan (+ mean-pool) ----------------
// Ap: bf16 plane [Mm+128][K].  Wh/Wl: frag-packed.  Hout: bf16 plane [Mm+128][H].
// SUBR=64 rows/sub-tile (5 phases/chunk). W fragments hoisted to VGPRs once per
// block (removes per-phase L2 W reads + latency). A staging double-buffered:
// stage(t+1) issued between MFMA(t) and epilogue(t) so global latency hides
// under epilogue VALU. Barriers: 2/phase (3 for POOL).
template <int K, int H, bool POOL>
__global__ __launch_bounds__(512) void qrnn_fused(const short* __restrict__ Ap,
                                                  const short* __restrict__ Wh,
                                                  const short* __restrict__ Wl,
                                                  const float* __restrict__ bias,
                                                  short* __restrict__ Hout,
                                                  float* __restrict__ pooled) {
    constexpr int SUBR = 64;                      // rows per sub-tile
    constexpr int NT = 256 / SUBR;                // sub-tiles per chunk
    constexpr int NS = K / 32;                    // k-steps
    constexpr int WN = (H / 16 < 8) ? (H / 16) : 8;  // col wave-groups
    constexpr int WR = 8 / WN;                    // row wave-groups
    constexpr int NZF = H / (16 * WN);            // z col-frags per wave
    constexpr int RPW = SUBR / WR;                // rows per wave
    constexpr int RF = RPW / 16;                  // row frags per wave
    constexpr int LDA = K + 8;                    // padded LDS stride (halves)
    constexpr int ZP = H + 4;                     // zfs stride (words)
    constexpr int CH = K / 8;                     // 16B chunks per row

    __shared__ short As[2 * SUBR * LDA];
    __shared__ unsigned zfs[SUBR][ZP];

    const int tid = threadIdx.x;
    const int lane = tid & 63;
    const int w = tid >> 6;
    const int rg = w / WN, cg = w % WN;
    const int l15 = lane & 15, lh = lane >> 4;

    const int bi = blockIdx.x;
    const int b = bi / NCK, ck = bi % NCK;
    const int s0 = ck * 256;

    // ---- hoist W fragments into registers (once per block) ----
    bs8 wzh[NS * NZF], wzl[NS * NZF], wfh[NS * NZF], wfl[NS * NZF];
#pragma unroll
    for (int s = 0; s < NS; ++s)
#pragma unroll
        for (int nz = 0; nz < NZF; ++nz) {
            const int fz = cg * NZF + nz;
            const int ff = H / 16 + fz;
            wzh[s * NZF + nz] = *(const bs8*)&Wh[(((size_t)fz * NS + s) * 64 + lane) * 8];
            wzl[s * NZF + nz] = *(const bs8*)&Wl[(((size_t)fz * NS + s) * 64 + lane) * 8];
            wfh[s * NZF + nz] = *(const bs8*)&Wh[(((size_t)ff * NS + s) * 64 + lane) * 8];
            wfl[s * NZF + nz] = *(const bs8*)&Wl[(((size_t)ff * NS + s) * 64 + lane) * 8];
        }

    float hscan = 0.f;                            // per scan-thread fo-pool state
    const int tstart = (ck == 0) ? 0 : -1;        // 1 warmup sub-tile = 64 steps

    // ---- prologue: stage first sub-tile into buffer 0 ----
    {
        const size_t grow0 = (size_t)b * Ss + s0 + tstart * SUBR;
        for (int q = tid; q < SUBR * CH; q += 512) {
            int r = q / CH, hq = q % CH;
            *(bs8*)&As[r * LDA + hq * 8] = *(const bs8*)&Ap[(grow0 + r) * K + hq * 8];
        }
    }
    __syncthreads();

    for (int t = tstart; t < NT; ++t) {
        const int st = s0 + t * SUBR;
        if (st >= Ss) break;
        const int cur = (t - tstart) & 1;
        const short* Ac = &As[cur * SUBR * LDA];

        // ---- MFMA from As[cur] + register-resident W ----
        f32x4 acc[RF][2 * NZF];
#pragma unroll
        for (int i = 0; i < RF; ++i)
#pragma unroll
            for (int j = 0; j < 2 * NZF; ++j) acc[i][j] = (f32x4)0.f;

#pragma unroll
        for (int s = 0; s < NS; ++s) {
            bs8 ah[RF];
#pragma unroll
            for (int i = 0; i < RF; ++i)
                ah[i] = *(const bs8*)&Ac[(rg * RPW + i * 16 + l15) * LDA + s * 32 + lh * 8];
#pragma unroll
            for (int nz = 0; nz < NZF; ++nz) {
                const int wi_ = s * NZF + nz;
#pragma unroll
                for (int i = 0; i < RF; ++i) {
                    acc[i][nz] = __builtin_amdgcn_mfma_f32_16x16x32_bf16(ah[i], wzh[wi_], acc[i][nz], 0, 0, 0);
                    acc[i][nz] = __builtin_amdgcn_mfma_f32_16x16x32_bf16(ah[i], wzl[wi_], acc[i][nz], 0, 0, 0);
                    acc[i][NZF + nz] = __builtin_amdgcn_mfma_f32_16x16x32_bf16(ah[i], wfh[wi_], acc[i][NZF + nz], 0, 0, 0);
                    acc[i][NZF + nz] = __builtin_amdgcn_mfma_f32_16x16x32_bf16(ah[i], wfl[wi_], acc[i][NZF + nz], 0, 0, 0);
                }
            }
        }

        // ---- issue next-sub-tile stage into the other buffer (hides under epilogue) ----
        if (t + 1 < NT && s0 + (t + 1) * SUBR < Ss) {
            const size_t g2 = (size_t)b * Ss + s0 + (t + 1) * SUBR;
            short* An = &As[(cur ^ 1) * SUBR * LDA];
            for (int q = tid; q < SUBR * CH; q += 512) {
                int r = q / CH, hq = q % CH;
                *(bs8*)&An[r * LDA + hq * 8] = *(const bs8*)&Ap[(g2 + r) * K + hq * 8];
            }
        }

        // ---- epilogue: bias + activations, pack (z,f) -> zfs ----
#pragma unroll
        for (int nz = 0; nz < NZF; ++nz) {
            const int c = cg * (16 * NZF) + nz * 16 + l15;
            const float bz = bias[c], bfv = bias[H + c];
#pragma unroll
            for (int i = 0; i < RF; ++i) {
                const int rbase = rg * RPW + i * 16 + lh * 4;
#pragma unroll
                for (int r = 0; r < 4; ++r) {
                    float zv = fast_tanh(acc[i][nz][r] + bz);
                    float fv = fast_sigmoid(acc[i][NZF + nz][r] + bfv);
                    zfs[rbase + r][c] = (((unsigned)f2bf(zv)) << 16) | (unsigned)f2bf(fv);
                }
            }
        }
        __syncthreads();   // zfs ready; As[cur^1] staged (drained)

        // ---- fo-pool scan over the SUBR rows (thread c owns channel c) ----
        if (tid < H) {
            const int c = tid;
            float h = hscan;
#pragma unroll 8
            for (int r = 0; r < SUBR; ++r) {
                unsigned u = zfs[r][c];
                float z = bf2f((unsigned short)(u >> 16));
                float f = bf2f((unsigned short)(u & 0xFFFF));
                h = fmaf(f, h - z, z);
                if (POOL) {
                    zfs[r][c] = __float_as_uint(h);
                } else {
                    int s = st + r;
                    if (t >= 0 && s < Ss)
                        Hout[((size_t)b * Ss + s) * H + c] = (short)f2bf(h);
                }
            }
            hscan = h;
        }
        __syncthreads();   // zfs (h values) visible to pool / free for next epilogue

        if (POOL) {
            if (t >= 0) {
                // 8 waves x 8 rows: shuffle-reduce 256 channels -> pooled
#pragma unroll
                for (int rr = 0; rr < SUBR / 8; ++rr) {
                    const int r = w * (SUBR / 8) + rr;
                    float sum = __uint_as_float(zfs[r][lane]) +
                                __uint_as_float(zfs[r][lane + 64]) +
                                __uint_as_float(zfs[r][lane + 128]) +
                                __uint_as_float(zfs[r][lane + 192]);
#pragma unroll
                    for (int off = 32; off >= 1; off >>= 1)
                        sum += __shfl_xor(sum, off, 64);
                    int s = st + r;
                    if (lane == 0 && s < Ss)
                        pooled[(size_t)b * Ss + s] = sum * (1.f / 256.f);
                }
            }
            __syncthreads();
        }
    }
}

// ---------------- small fp32 GEMM (layers with K<32) ----------------
template <int K>
__global__ __launch_bounds__(256) void qrnn_gemm(const float* __restrict__ A,
                                                 const float* __restrict__ W,
                                                 const float* __restrict__ bias,
                                                 float* __restrict__ ZF,
                                                 int Nfull, int Wout, int Hg, int z0, int f0) {
    constexpr int BM = 64, BN = 64;
    constexpr int BK = (K < 32) ? K : 32;
    __shared__ float As[BK][BM + 4];
    __shared__ float Bs[BK][BN];
    const int tid = threadIdx.x;
    const int tx = tid % 16, ty = tid / 16;
    const int m0 = blockIdx.x * BM;
    const int n0 = blockIdx.y * BN;
    float acc[4][4] = {};

    for (int k0 = 0; k0 < K; k0 += BK) {
        constexpr int KQ = BK / 4;
        constexpr int AV = BM * KQ;
        for (int v = tid; v < AV; v += 256) {
            int m = v / KQ, kq = v % KQ;
            float4 av = *(const float4*)&A[(size_t)(m0 + m) * K + k0 + kq * 4];
            As[kq * 4 + 0][m] = av.x;
            As[kq * 4 + 1][m] = av.y;
            As[kq * 4 + 2][m] = av.z;
            As[kq * 4 + 3][m] = av.w;
        }
        constexpr int BV = BK * 16;
        for (int v = tid; v < BV; v += 256) {
            int ki = v / 16, nq = v % 16;
            int j = n0 + nq * 4;
            float4 bv = make_float4(0.f, 0.f, 0.f, 0.f);
            if (j < Wout) {
                int wc = (j < Hg) ? (z0 + j) : (f0 + (j - Hg));
                bv = *(const float4*)&W[(size_t)(k0 + ki) * Nfull + wc];
            }
            *(float4*)&Bs[ki][nq * 4] = bv;
        }
        __syncthreads();
#pragma unroll
        for (int kk = 0; kk < BK; ++kk) {
            float a[4];
#pragma unroll
            for (int i = 0; i < 4; ++i) a[i] = As[kk][ty * 4 + i];
            float4 bv = *(const float4*)&Bs[kk][tx * 4];
            float bb[4] = {bv.x, bv.y, bv.z, bv.w};
#pragma unroll
            for (int i = 0; i < 4; ++i)
#pragma unroll
                for (int j = 0; j < 4; ++j) acc[i][j] = fmaf(a[i], bb[j], acc[i][j]);
        }
        __syncthreads();
    }
    int jb = n0 + tx * 4;
    if (jb < Wout) {
        bool isz = jb < Hg;
#pragma unroll
        for (int i = 0; i < 4; ++i) {
            int gm = m0 + ty * 4 + i;
            float o[4];
#pragma unroll
            for (int jj = 0; jj < 4; ++jj) {
                int j = jb + jj;
                int wc = isz ? (z0 + j) : (f0 + (j - Hg));
                float v = acc[i][jj] + bias[wc];
                o[jj] = isz ? fast_tanh(v) : fast_sigmoid(v);
            }
            *(float4*)&ZF[(size_t)gm * Wout + jb] = make_float4(o[0], o[1], o[2], o[3]);
        }
    }
}

// ---------------- scans for small layers ----------------
// fp32 zf -> fp32 compact h (after layer0)
__global__ void scan_f2c(const float* __restrict__ zf, float* __restrict__ hout,
                         int Hg, int W2, int Hfull, int ch0) {
    int id = blockIdx.x * blockDim.x + threadIdx.x;
    int total = Bb * NCH * Hg;
    if (id >= total) return;
    int c = id % Hg;
    int p = id / Hg;
    int b = p / NCH, ck = p % NCH;
    int sc = ck * CLEN;
    float h = 0.f;
    if (ck) {
#pragma unroll 4
        for (int s = sc - WARM; s < sc; ++s) {
            size_t base = (size_t)(b * Ss + s) * W2;
            float z = zf[base + c], f = zf[base + Hg + c];
            h = fmaf(f, h - z, z);
        }
    }
#pragma unroll 5
    for (int s = sc; s < sc + CLEN; ++s) {
        size_t base = (size_t)(b * Ss + s) * W2;
        float z = zf[base + c], f = zf[base + Hg + c];
        h = fmaf(f, h - z, z);
        hout[(size_t)(b * Ss + s) * Hfull + ch0 + c] = h;
    }
}

// fp32 zf -> bf16 plane (after layer1)
__global__ void scan_f2p(const float* __restrict__ zf, short* __restrict__ Ahp,
                         int Hg, int W2, int Kn, int ch0) {
    int id = blockIdx.x * blockDim.x + threadIdx.x;
    int total = Bb * NCH * Hg;
    if (id >= total) return;
    int c = id % Hg;
    int p = id / Hg;
    int b = p / NCH, ck = p % NCH;
    int sc = ck * CLEN;
    float h = 0.f;
    if (ck) {
#pragma unroll 4
        for (int s = sc - WARM; s < sc; ++s) {
            size_t base = (size_t)(b * Ss + s) * W2;
            float z = zf[base + c], f = zf[base + Hg + c];
            h = fmaf(f, h - z, z);
        }
    }
#pragma unroll 5
    for (int s = sc; s < sc + CLEN; ++s) {
        size_t base = (size_t)(b * Ss + s) * W2;
        float z = zf[base + c], f = zf[base + Hg + c];
        h = fmaf(f, h - z, z);
        Ahp[(size_t)(b * Ss + s) * Kn + ch0 + c] = (short)f2bf(h);
    }
}

// ---------------- MLP ----------------
__global__ __launch_bounds__(256) void mlp1_kernel(const float* __restrict__ xp,
                                                   const float* __restrict__ w1,
                                                   float* __restrict__ parts) {
    const int n0 = blockIdx.x * 64;
    const int ks = blockIdx.y;
    const int kbeg = ks * 250;
    const int nl = threadIdx.x % 64, mg = threadIdx.x / 64;
    __shared__ float xs[50][68];
    float acc[16] = {};
    for (int kc = 0; kc < 5; ++kc) {
        int k0 = kbeg + kc * 50;
        __syncthreads();
        for (int idx = threadIdx.x; idx < 64 * 50; idx += 256) {
            int r = idx / 50, cc = idx % 50;
            xs[cc][r] = xp[r * Ss + k0 + cc];
        }
        __syncthreads();
#pragma unroll 5
        for (int kk = 0; kk < 50; ++kk) {
            float wv = w1[(size_t)(k0 + kk) * 1024 + n0 + nl];
#pragma unroll
            for (int q = 0; q < 4; ++q) {
                float4 xv = *(const float4*)&xs[kk][mg * 16 + q * 4];
                acc[q * 4 + 0] = fmaf(xv.x, wv, acc[q * 4 + 0]);
                acc[q * 4 + 1] = fmaf(xv.y, wv, acc[q * 4 + 1]);
                acc[q * 4 + 2] = fmaf(xv.z, wv, acc[q * 4 + 2]);
                acc[q * 4 + 3] = fmaf(xv.w, wv, acc[q * 4 + 3]);
            }
        }
    }
#pragma unroll
    for (int i = 0; i < 16; ++i) {
        int m = mg * 16 + i;
        parts[((size_t)ks * 64 + m) * 1024 + n0 + nl] = acc[i];
    }
}

__global__ void mlp1_reduce(const float* __restrict__ parts, const float* __restrict__ b1,
                            float* __restrict__ h1) {
    int id = blockIdx.x * 256 + threadIdx.x;
    int n = id % 1024, m = id / 1024;
    float s = b1[n];
#pragma unroll
    for (int ks = 0; ks < 12; ++ks) s += parts[((size_t)ks * 64 + m) * 1024 + n];
    h1[id] = fmaxf(s, 0.f);
}

__global__ void mlp2_kernel(const float* __restrict__ h1, const float* __restrict__ w2,
                            const float* __restrict__ b2, float* __restrict__ h2) {
    int m = blockIdx.x, n = threadIdx.x;
    float acc = 0.f;
#pragma unroll 8
    for (int k = 0; k < 1024; ++k) acc = fmaf(h1[m * 1024 + k], w2[k * 128 + n], acc);
    h2[m * 128 + n] = fmaxf(acc + b2[n], 0.f);
}

__global__ void mlp3_kernel(const float* __restrict__ h2, const float* __restrict__ w3,
                            const float* __restrict__ b3, float* __restrict__ out) {
    int t = threadIdx.x;
    if (t >= 640) return;
    int m = t / 10, n = t % 10;
    float acc = 0.f;
#pragma unroll
    for (int k = 0; k < 128; ++k) acc = fmaf(h2[m * 128 + k], w3[k * 10 + n], acc);
    out[t] = fmaxf(acc + b3[n], 0.f);
}

// ---------------- launcher ----------------
extern "C" void kernel_launch(void* const* d_in, const int* in_sizes, int n_in,
                              void* d_out, int out_size, void* d_ws, size_t ws_size,
                              hipStream_t stream) {
    const float* x   = (const float*)d_in[0];
    const float* wih = (const float*)d_in[1];
    const float* whh = (const float*)d_in[2];
    const float* bih = (const float*)d_in[3];
    const float* bhh = (const float*)d_in[4];
    const float* qw[5] = {(const float*)d_in[5], (const float*)d_in[7], (const float*)d_in[9],
                          (const float*)d_in[11], (const float*)d_in[13]};
    const float* qb[5] = {(const float*)d_in[6], (const float*)d_in[8], (const float*)d_in[10],
                          (const float*)d_in[12], (const float*)d_in[14]};
    const float* w1 = (const float*)d_in[15];
    const float* b1 = (const float*)d_in[16];
    const float* w2 = (const float*)d_in[17];
    const float* b2 = (const float*)d_in[18];
    const float* w3 = (const float*)d_in[19];
    const float* b3 = (const float*)d_in[20];
    float* out = (float*)d_out;

    // ---- ws carve ----
    char* ws = (char*)d_ws;
    size_t off = 0;
    auto carve = [&](size_t sz) {
        char* q = ws + off;
        off += (sz + 255) & ~size_t(255);
        return q;
    };
    float* h4    = (float*)carve((size_t)Mm * 4 * 4);              // RNN out
    float* h16   = (float*)carve((size_t)Mm * 16 * 4);             // L0 out (fp32)
    float* zf32  = (float*)carve((size_t)Mm * 64 * 4);             // L0/L1 zf buffer
    short* p32   = (short*)carve((size_t)(Mm + 128) * 32 * 2);     // L1 out plane
    short* p64   = (short*)carve((size_t)(Mm + 128) * 64 * 2);     // L2 out plane
    short* p128  = (short*)carve((size_t)(Mm + 128) * 128 * 2);    // L3 out plane
    float* pooled = (float*)carve((size_t)Bb * Ss * 4);
    float* parts  = (float*)carve(12ull * 64 * 1024 * 4);
    float* h1m    = (float*)carve(64ull * 1024 * 4);
    float* h2m    = (float*)carve(64ull * 128 * 4);
    short* wh2 = (short*)carve(4096 * 2);
    short* wl2 = (short*)carve(4096 * 2);
    short* wh3 = (short*)carve(16384 * 2);
    short* wl3 = (short*)carve(16384 * 2);
    short* wh4 = (short*)carve(65536 * 2);
    short* wl4 = (short*)carve(65536 * 2);
    (void)ws_size;

    // ---- weight prep (frag-packed bf16 hi/lo) ----
    prep_wfrag<<<8,  256, 0, stream>>>(qw[2], wh2, wl2, 32, 128);
    prep_wfrag<<<16, 256, 0, stream>>>(qw[3], wh3, wl3, 64, 256);
    prep_wfrag<<<64, 256, 0, stream>>>(qw[4], wh4, wl4, 128, 512);

    // ---- RNN ----
    rnn_kernel2<<<Bb, 64, 0, stream>>>(x, wih, whh, bih, bhh, h4);

    // ---- layer0 (K=4, H=16): fp32 gemm + scan -> h16 ----
    {
        dim3 grid(Mm / 64, 1);
        qrnn_gemm<4><<<grid, 256, 0, stream>>>(h4, qw[0], qb[0], zf32, 32, 32, 16, 0, 16);
        int total = Bb * NCH * 16;
        scan_f2c<<<(total + 255) / 256, 256, 0, stream>>>(zf32, h16, 16, 32, 16, 0);
    }
    // ---- layer1 (K=16, H=32): fp32 gemm + scan -> bf16 plane p32 ----
    {
        dim3 grid(Mm / 64, 1);
        qrnn_gemm<16><<<grid, 256, 0, stream>>>(h16, qw[1], qb[1], zf32, 64, 64, 32, 0, 32);
        int total = Bb * NCH * 32;
        scan_f2p<<<(total + 255) / 256, 256, 0, stream>>>(zf32, p32, 32, 64, 32, 0);
    }
    // ---- fused layers 2..4 ----
    qrnn_fused<32, 64, false><<<Bb * NCK, 512, 0, stream>>>(p32, wh2, wl2, qb[2], p64, nullptr);
    qrnn_fused<64, 128, false><<<Bb * NCK, 512, 0, stream>>>(p64, wh3, wl3, qb[3], p128, nullptr);
    qrnn_fused<128, 256, true><<<Bb * NCK, 512, 0, stream>>>(p128, wh4, wl4, qb[4], nullptr, pooled);

    // ---- MLP ----
    mlp1_kernel<<<dim3(16, 12), 256, 0, stream>>>(pooled, w1, parts);
    mlp1_reduce<<<256, 256, 0, stream>>>(parts, b1, h1m);
    mlp2_kernel<<<64, 128, 0, stream>>>(h1m, w2, b2, h2m);
    mlp3_kernel<<<1, 640, 0, stream>>>(h2m, w3, b3, out);
    (void)in_sizes; (void)n_in; (void)out_size;
}

// Round 13
// 531.985 us; speedup vs baseline: 2.6492x; 1.0384x over previous
//
#include <hip/hip_runtime.h>
#include <hip/hip_bf16.h>

#define DEVI __device__ __forceinline__

static constexpr int Bb = 64;
static constexpr int Ss = 3000;
static constexpr int Mm = Bb * Ss;      // 192000
static constexpr int NCH = 12;          // sequence chunks (L0/L1 scans)
static constexpr int CLEN = 250;        // chunk length (L0/L1 scans)
static constexpr int WARM = 64;         // scan warmup steps
static constexpr int RCH = 60;          // rnn chunks
static constexpr int RCLEN = 50;        // rnn chunk length
static constexpr int RWARM = 32;        // rnn warmup steps

typedef short bs8 __attribute__((ext_vector_type(8)));
typedef float f32x4 __attribute__((ext_vector_type(4)));

// fast activations: v_exp + v_rcp (1-ulp rcp; fine vs bf16 storage)
DEVI float fast_tanh(float x) {
    float e = __expf(2.0f * x);
    return 1.0f - 2.0f * __builtin_amdgcn_rcpf(e + 1.0f);
}
DEVI float fast_sigmoid(float x) {
    return __builtin_amdgcn_rcpf(1.0f + __expf(-x));
}
DEVI unsigned short f2bf(float f) {
    unsigned u = __float_as_uint(f);
    u += 0x7FFF + ((u >> 16) & 1);
    return (unsigned short)(u >> 16);
}
DEVI float bf2f(unsigned short h) { return __uint_as_float(((unsigned)h) << 16); }
// packed (z,f) -> u32 via v_cvt_pk_bf16_f32 (RTNE, same as f2bf)
DEVI unsigned pack_zf(float zv, float fv) {
    __hip_bfloat162 p = __float22bfloat162_rn(float2{fv, zv});   // x=low=f, y=high=z
    return *reinterpret_cast<unsigned*>(&p);
}
DEVI short bf16s(float v) {
    __hip_bfloat16 b = __float2bfloat16(v);
    return *reinterpret_cast<short*>(&b);
}

// ---------------- RNN (hidden=4): LDS-staged x, 60 chunks/batch ----------------
__global__ __launch_bounds__(64) void rnn_kernel2(const float* __restrict__ x,
                                                  const float* __restrict__ wih,
                                                  const float* __restrict__ whh,
                                                  const float* __restrict__ bih,
                                                  const float* __restrict__ bhh,
                                                  float* __restrict__ hout) {
    __shared__ float xs[Ss];
    int b = blockIdx.x;
    for (int i = threadIdx.x; i < Ss / 4; i += 64) {
        *(float4*)&xs[i * 4] = *(const float4*)&x[b * Ss + i * 4];
    }
    __syncthreads();
    int ck = threadIdx.x;
    if (ck >= RCH) return;
    float w[4][4], wi[4], bc[4];
#pragma unroll
    for (int j = 0; j < 4; ++j) {
        wi[j] = wih[j];
        bc[j] = bih[j] + bhh[j];
#pragma unroll
        for (int i = 0; i < 4; ++i) w[j][i] = whh[j * 4 + i];
    }
    float h0 = 0.f, h1 = 0.f, h2 = 0.f, h3 = 0.f;
    int sc = ck * RCLEN;
    int sb = ck ? (sc - RWARM) : 0;
#pragma unroll 4
    for (int s = sb; s < sc; ++s) {
        float xv = xs[s];
        float n0 = fast_tanh(fmaf(xv, wi[0], bc[0]) + w[0][0]*h0 + w[0][1]*h1 + w[0][2]*h2 + w[0][3]*h3);
        float n1 = fast_tanh(fmaf(xv, wi[1], bc[1]) + w[1][0]*h0 + w[1][1]*h1 + w[1][2]*h2 + w[1][3]*h3);
        float n2 = fast_tanh(fmaf(xv, wi[2], bc[2]) + w[2][0]*h0 + w[2][1]*h1 + w[2][2]*h2 + w[2][3]*h3);
        float n3 = fast_tanh(fmaf(xv, wi[3], bc[3]) + w[3][0]*h0 + w[3][1]*h1 + w[3][2]*h2 + w[3][3]*h3);
        h0 = n0; h1 = n1; h2 = n2; h3 = n3;
    }
#pragma unroll 5
    for (int s = sc; s < sc + RCLEN; ++s) {
        float xv = xs[s];
        float n0 = fast_tanh(fmaf(xv, wi[0], bc[0]) + w[0][0]*h0 + w[0][1]*h1 + w[0][2]*h2 + w[0][3]*h3);
        float n1 = fast_tanh(fmaf(xv, wi[1], bc[1]) + w[1][0]*h0 + w[1][1]*h1 + w[1][2]*h2 + w[1][3]*h3);
        float n2 = fast_tanh(fmaf(xv, wi[2], bc[2]) + w[2][0]*h0 + w[2][1]*h1 + w[2][2]*h2 + w[2][3]*h3);
        float n3 = fast_tanh(fmaf(xv, wi[3], bc[3]) + w[3][0]*h0 + w[3][1]*h1 + w[3][2]*h2 + w[3][3]*h3);
        h0 = n0; h1 = n1; h2 = n2; h3 = n3;
        *(float4*)&hout[(size_t)(b * Ss + s) * 4] = make_float4(h0, h1, h2, h3);
    }
}

// -------- weight prep: W (K,2H) fp32 -> frag-packed bf16 hi/lo planes --------
// Layout: [frag=n/16][s=k/32][lane=(n&15)|(((k>>3)&3)<<4)][elem=k&7]
__global__ void prep_wfrag(const float* __restrict__ W, short* __restrict__ Wh,
                           short* __restrict__ Wl, int K, int N2) {
    int total = K * N2;
    int NS = K / 32;
    for (int t = blockIdx.x * blockDim.x + threadIdx.x; t < total; t += gridDim.x * blockDim.x) {
        int n = t / K, k = t % K;
        float w = W[(size_t)k * N2 + n];
        int frag = n >> 4;
        int s = k >> 5;
        int lane = (n & 15) | (((k >> 3) & 3) << 4);
        int elem = k & 7;
        size_t off = (((size_t)(frag * NS + s)) * 64 + lane) * 8 + elem;
        unsigned short h = f2bf(w);
        Wh[off] = (short)h;
        Wl[off] = (short)f2bf(w - bf2f(h));
    }
}

// ---------------- fused MFMA GEMM + fo-pool scan (+ mean-pool) ----------------
// Ap: bf16 plane [Mm+128][K].  Wh/Wl: frag-packed.  Hout: bf16 plane [Mm+128][H].
// SUBR=64 rows/sub-tile.  W fragments VGPR-resident once per block; A staging
// double-buffered (stage(t+1) issued between MFMA(t) and epilogue(t)).
// CHUNK: steps per block (768 for L4 -> 256 blocks = 1/CU in a single round,
// warmup phases 1/13; 256 for L2/L3 which have multi-block residency).
template <int K, int H, bool POOL, int CHUNK>
DEVI void qrnn_fused_impl(const short* __restrict__ Ap,
                          const short* __restrict__ Wh,
                          const short* __restrict__ Wl,
                          const float* __restrict__ bias,
                          short* __restrict__ Hout,
                          float* __restrict__ pooled) {
    constexpr int SUBR = 64;                      // rows per sub-tile
    constexpr int NT = CHUNK / SUBR;              // sub-tiles per chunk
    constexpr int NCKL = (Ss + CHUNK - 1) / CHUNK;
    constexpr int NS = K / 32;                    // k-steps
    constexpr int WN = (H / 16 < 8) ? (H / 16) : 8;  // col wave-groups
    constexpr int WR = 8 / WN;                    // row wave-groups
    constexpr int NZF = H / (16 * WN);            // z col-frags per wave
    constexpr int RPW = SUBR / WR;                // rows per wave
    constexpr int RF = RPW / 16;                  // row frags per wave
    constexpr int LDA = K + 8;                    // padded LDS stride (halves)
    constexpr int ZP = H + 4;                     // zfs stride (words)
    constexpr int CH = K / 8;                     // 16B chunks per row

    __shared__ short As[2 * SUBR * LDA];
    __shared__ unsigned zfs[SUBR][ZP];

    const int tid = threadIdx.x;
    const int lane = tid & 63;
    const int w = tid >> 6;
    const int rg = w / WN, cg = w % WN;
    const int l15 = lane & 15, lh = lane >> 4;

    const int bi = blockIdx.x;
    const int b = bi / NCKL, ck = bi % NCKL;
    const int s0 = ck * CHUNK;

    // ---- hoist W fragments into registers (once per block) ----
    bs8 wzh[NS * NZF], wzl[NS * NZF], wfh[NS * NZF], wfl[NS * NZF];
#pragma unroll
    for (int s = 0; s < NS; ++s)
#pragma unroll
        for (int nz = 0; nz < NZF; ++nz) {
            const int fz = cg * NZF + nz;
            const int ff = H / 16 + fz;
            wzh[s * NZF + nz] = *(const bs8*)&Wh[(((size_t)fz * NS + s) * 64 + lane) * 8];
            wzl[s * NZF + nz] = *(const bs8*)&Wl[(((size_t)fz * NS + s) * 64 + lane) * 8];
            wfh[s * NZF + nz] = *(const bs8*)&Wh[(((size_t)ff * NS + s) * 64 + lane) * 8];
            wfl[s * NZF + nz] = *(const bs8*)&Wl[(((size_t)ff * NS + s) * 64 + lane) * 8];
        }

    float hscan = 0.f;                            // per scan-thread fo-pool state
    const int tstart = (ck == 0) ? 0 : -1;        // 1 warmup sub-tile = 64 steps

    // ---- prologue: stage first sub-tile into buffer 0 ----
    {
        const size_t grow0 = (size_t)b * Ss + s0 + tstart * SUBR;
        for (int q = tid; q < SUBR * CH; q += 512) {
            int r = q / CH, hq = q % CH;
            *(bs8*)&As[r * LDA + hq * 8] = *(const bs8*)&Ap[(grow0 + r) * K + hq * 8];
        }
    }
    __syncthreads();

    for (int t = tstart; t < NT; ++t) {
        const int st = s0 + t * SUBR;
        if (st >= Ss) break;
        const int cur = (t - tstart) & 1;
        const short* Ac = &As[cur * SUBR * LDA];

        // ---- MFMA from As[cur] + register-resident W ----
        f32x4 acc[RF][2 * NZF];
#pragma unroll
        for (int i = 0; i < RF; ++i)
#pragma unroll
            for (int j = 0; j < 2 * NZF; ++j) acc[i][j] = (f32x4)0.f;

#pragma unroll
        for (int s = 0; s < NS; ++s) {
            bs8 ah[RF];
#pragma unroll
            for (int i = 0; i < RF; ++i)
                ah[i] = *(const bs8*)&Ac[(rg * RPW + i * 16 + l15) * LDA + s * 32 + lh * 8];
#pragma unroll
            for (int nz = 0; nz < NZF; ++nz) {
                const int wi_ = s * NZF + nz;
#pragma unroll
                for (int i = 0; i < RF; ++i) {
                    acc[i][nz] = __builtin_amdgcn_mfma_f32_16x16x32_bf16(ah[i], wzh[wi_], acc[i][nz], 0, 0, 0);
                    acc[i][nz] = __builtin_amdgcn_mfma_f32_16x16x32_bf16(ah[i], wzl[wi_], acc[i][nz], 0, 0, 0);
                    acc[i][NZF + nz] = __builtin_amdgcn_mfma_f32_16x16x32_bf16(ah[i], wfh[wi_], acc[i][NZF + nz], 0, 0, 0);
                    acc[i][NZF + nz] = __builtin_amdgcn_mfma_f32_16x16x32_bf16(ah[i], wfl[wi_], acc[i][NZF + nz], 0, 0, 0);
                }
            }
        }

        // ---- issue next-sub-tile stage into the other buffer (hides under epilogue) ----
        if (t + 1 < NT && s0 + (t + 1) * SUBR < Ss) {
            const size_t g2 = (size_t)b * Ss + s0 + (t + 1) * SUBR;
            short* An = &As[(cur ^ 1) * SUBR * LDA];
            for (int q = tid; q < SUBR * CH; q += 512) {
                int r = q / CH, hq = q % CH;
                *(bs8*)&An[r * LDA + hq * 8] = *(const bs8*)&Ap[(g2 + r) * K + hq * 8];
            }
        }

        // ---- epilogue: bias + activations, v_cvt_pk pack (z,f) -> zfs ----
#pragma unroll
        for (int nz = 0; nz < NZF; ++nz) {
            const int c = cg * (16 * NZF) + nz * 16 + l15;
            const float bz = bias[c], bfv = bias[H + c];
#pragma unroll
            for (int i = 0; i < RF; ++i) {
                const int rbase = rg * RPW + i * 16 + lh * 4;
#pragma unroll
                for (int r = 0; r < 4; ++r) {
                    float zv = fast_tanh(acc[i][nz][r] + bz);
                    float fv = fast_sigmoid(acc[i][NZF + nz][r] + bfv);
                    zfs[rbase + r][c] = pack_zf(zv, fv);
                }
            }
        }
        __syncthreads();   // zfs ready; As[cur^1] staged (drained)

        // ---- fo-pool scan over the SUBR rows (thread c owns channel c) ----
        if (tid < H) {
            const int c = tid;
            float h = hscan;
#pragma unroll 8
            for (int r = 0; r < SUBR; ++r) {
                unsigned u = zfs[r][c];
                float z = bf2f((unsigned short)(u >> 16));
                float f = bf2f((unsigned short)(u & 0xFFFF));
                h = fmaf(f, h - z, z);
                if (POOL) {
                    zfs[r][c] = __float_as_uint(h);
                } else {
                    int s = st + r;
                    if (t >= 0 && s < Ss)
                        Hout[((size_t)b * Ss + s) * H + c] = bf16s(h);
                }
            }
            hscan = h;
        }
        __syncthreads();   // zfs (h values) visible to pool / free for next epilogue

        if (POOL) {
            if (t >= 0) {
                // 8 waves x 8 rows: shuffle-reduce 256 channels -> pooled
#pragma unroll
                for (int rr = 0; rr < SUBR / 8; ++rr) {
                    const int r = w * (SUBR / 8) + rr;
                    float sum = __uint_as_float(zfs[r][lane]) +
                                __uint_as_float(zfs[r][lane + 64]) +
                                __uint_as_float(zfs[r][lane + 128]) +
                                __uint_as_float(zfs[r][lane + 192]);
#pragma unroll
                    for (int off = 32; off >= 1; off >>= 1)
                        sum += __shfl_xor(sum, off, 64);
                    int s = st + r;
                    if (lane == 0 && s < Ss)
                        pooled[(size_t)b * Ss + s] = sum * (1.f / 256.f);
                }
            }
            __syncthreads();
        }
    }
}

__global__ __launch_bounds__(512) void qrnn_fused_l2(const short* __restrict__ Ap,
                                                     const short* __restrict__ Wh,
                                                     const short* __restrict__ Wl,
                                                     const float* __restrict__ bias,
                                                     short* __restrict__ Hout) {
    qrnn_fused_impl<32, 64, false, 256>(Ap, Wh, Wl, bias, Hout, nullptr);
}
__global__ __launch_bounds__(512) void qrnn_fused_l3(const short* __restrict__ Ap,
                                                     const short* __restrict__ Wh,
                                                     const short* __restrict__ Wl,
                                                     const float* __restrict__ bias,
                                                     short* __restrict__ Hout) {
    qrnn_fused_impl<64, 128, false, 256>(Ap, Wh, Wl, bias, Hout, nullptr);
}
__global__ __launch_bounds__(512) void qrnn_fused_l4(const short* __restrict__ Ap,
                                                     const short* __restrict__ Wh,
                                                     const short* __restrict__ Wl,
                                                     const float* __restrict__ bias,
                                                     float* __restrict__ pooled) {
    qrnn_fused_impl<128, 256, true, 768>(Ap, Wh, Wl, bias, nullptr, pooled);
}

// ---------------- small fp32 GEMM (layers with K<32) ----------------
template <int K>
__global__ __launch_bounds__(256) void qrnn_gemm(const float* __restrict__ A,
                                                 const float* __restrict__ W,
                                                 const float* __restrict__ bias,
                                                 float* __restrict__ ZF,
                                                 int Nfull, int Wout, int Hg, int z0, int f0) {
    constexpr int BM = 64, BN = 64;
    constexpr int BK = (K < 32) ? K : 32;
    __shared__ float As[BK][BM + 4];
    __shared__ float Bs[BK][BN];
    const int tid = threadIdx.x;
    const int tx = tid % 16, ty = tid / 16;
    const int m0 = blockIdx.x * BM;
    const int n0 = blockIdx.y * BN;
    float acc[4][4] = {};

    for (int k0 = 0; k0 < K; k0 += BK) {
        constexpr int KQ = BK / 4;
        constexpr int AV = BM * KQ;
        for (int v = tid; v < AV; v += 256) {
            int m = v / KQ, kq = v % KQ;
            float4 av = *(const float4*)&A[(size_t)(m0 + m) * K + k0 + kq * 4];
            As[kq * 4 + 0][m] = av.x;
            As[kq * 4 + 1][m] = av.y;
            As[kq * 4 + 2][m] = av.z;
            As[kq * 4 + 3][m] = av.w;
        }
        constexpr int BV = BK * 16;
        for (int v = tid; v < BV; v += 256) {
            int ki = v / 16, nq = v % 16;
            int j = n0 + nq * 4;
            float4 bv = make_float4(0.f, 0.f, 0.f, 0.f);
            if (j < Wout) {
                int wc = (j < Hg) ? (z0 + j) : (f0 + (j - Hg));
                bv = *(const float4*)&W[(size_t)(k0 + ki) * Nfull + wc];
            }
            *(float4*)&Bs[ki][nq * 4] = bv;
        }
        __syncthreads();
#pragma unroll
        for (int kk = 0; kk < BK; ++kk) {
            float a[4];
#pragma unroll
            for (int i = 0; i < 4; ++i) a[i] = As[kk][ty * 4 + i];
            float4 bv = *(const float4*)&Bs[kk][tx * 4];
            float bb[4] = {bv.x, bv.y, bv.z, bv.w};
#pragma unroll
            for (int i = 0; i < 4; ++i)
#pragma unroll
                for (int j = 0; j < 4; ++j) acc[i][j] = fmaf(a[i], bb[j], acc[i][j]);
        }
        __syncthreads();
    }
    int jb = n0 + tx * 4;
    if (jb < Wout) {
        bool isz = jb < Hg;
#pragma unroll
        for (int i = 0; i < 4; ++i) {
            int gm = m0 + ty * 4 + i;
            float o[4];
#pragma unroll
            for (int jj = 0; jj < 4; ++jj) {
                int j = jb + jj;
                int wc = isz ? (z0 + j) : (f0 + (j - Hg));
                float v = acc[i][jj] + bias[wc];
                o[jj] = isz ? fast_tanh(v) : fast_sigmoid(v);
            }
            *(float4*)&ZF[(size_t)gm * Wout + jb] = make_float4(o[0], o[1], o[2], o[3]);
        }
    }
}

// ---------------- scans for small layers ----------------
// fp32 zf -> fp32 compact h (after layer0)
__global__ void scan_f2c(const float* __restrict__ zf, float* __restrict__ hout,
                         int Hg, int W2, int Hfull, int ch0) {
    int id = blockIdx.x * blockDim.x + threadIdx.x;
    int total = Bb * NCH * Hg;
    if (id >= total) return;
    int c = id % Hg;
    int p = id / Hg;
    int b = p / NCH, ck = p % NCH;
    int sc = ck * CLEN;
    float h = 0.f;
    if (ck) {
#pragma unroll 4
        for (int s = sc - WARM; s < sc; ++s) {
            size_t base = (size_t)(b * Ss + s) * W2;
            float z = zf[base + c], f = zf[base + Hg + c];
            h = fmaf(f, h - z, z);
        }
    }
#pragma unroll 5
    for (int s = sc; s < sc + CLEN; ++s) {
        size_t base = (size_t)(b * Ss + s) * W2;
        float z = zf[base + c], f = zf[base + Hg + c];
        h = fmaf(f, h - z, z);
        hout[(size_t)(b * Ss + s) * Hfull + ch0 + c] = h;
    }
}

// fp32 zf -> bf16 plane (after layer1)
__global__ void scan_f2p(const float* __restrict__ zf, short* __restrict__ Ahp,
                         int Hg, int W2, int Kn, int ch0) {
    int id = blockIdx.x * blockDim.x + threadIdx.x;
    int total = Bb * NCH * Hg;
    if (id >= total) return;
    int c = id % Hg;
    int p = id / Hg;
    int b = p / NCH, ck = p % NCH;
    int sc = ck * CLEN;
    float h = 0.f;
    if (ck) {
#pragma unroll 4
        for (int s = sc - WARM; s < sc; ++s) {
            size_t base = (size_t)(b * Ss + s) * W2;
            float z = zf[base + c], f = zf[base + Hg + c];
            h = fmaf(f, h - z, z);
        }
    }
#pragma unroll 5
    for (int s = sc; s < sc + CLEN; ++s) {
        size_t base = (size_t)(b * Ss + s) * W2;
        float z = zf[base + c], f = zf[base + Hg + c];
        h = fmaf(f, h - z, z);
        Ahp[(size_t)(b * Ss + s) * Kn + ch0 + c] = bf16s(h);
    }
}

// ---------------- MLP ----------------
__global__ __launch_bounds__(256) void mlp1_kernel(const float* __restrict__ xp,
                                                   const float* __restrict__ w1,
                                                   float* __restrict__ parts) {
    const int n0 = blockIdx.x * 64;
    const int ks = blockIdx.y;
    const int kbeg = ks * 250;
    const int nl = threadIdx.x % 64, mg = threadIdx.x / 64;
    __shared__ float xs[50][68];
    float acc[16] = {};
    for (int kc = 0; kc < 5; ++kc) {
        int k0 = kbeg + kc * 50;
        __syncthreads();
        for (int idx = threadIdx.x; idx < 64 * 50; idx += 256) {
            int r = idx / 50, cc = idx % 50;
            xs[cc][r] = xp[r * Ss + k0 + cc];
        }
        __syncthreads();
#pragma unroll 5
        for (int kk = 0; kk < 50; ++kk) {
            float wv = w1[(size_t)(k0 + kk) * 1024 + n0 + nl];
#pragma unroll
            for (int q = 0; q < 4; ++q) {
                float4 xv = *(const float4*)&xs[kk][mg * 16 + q * 4];
                acc[q * 4 + 0] = fmaf(xv.x, wv, acc[q * 4 + 0]);
                acc[q * 4 + 1] = fmaf(xv.y, wv, acc[q * 4 + 1]);
                acc[q * 4 + 2] = fmaf(xv.z, wv, acc[q * 4 + 2]);
                acc[q * 4 + 3] = fmaf(xv.w, wv, acc[q * 4 + 3]);
            }
        }
    }
#pragma unroll
    for (int i = 0; i < 16; ++i) {
        int m = mg * 16 + i;
        parts[((size_t)ks * 64 + m) * 1024 + n0 + nl] = acc[i];
    }
}

__global__ void mlp1_reduce(const float* __restrict__ parts, const float* __restrict__ b1,
                            float* __restrict__ h1) {
    int id = blockIdx.x * 256 + threadIdx.x;
    int n = id % 1024, m = id / 1024;
    float s = b1[n];
#pragma unroll
    for (int ks = 0; ks < 12; ++ks) s += parts[((size_t)ks * 64 + m) * 1024 + n];
    h1[id] = fmaxf(s, 0.f);
}

__global__ void mlp2_kernel(const float* __restrict__ h1, const float* __restrict__ w2,
                            const float* __restrict__ b2, float* __restrict__ h2) {
    int m = blockIdx.x, n = threadIdx.x;
    float acc = 0.f;
#pragma unroll 8
    for (int k = 0; k < 1024; ++k) acc = fmaf(h1[m * 1024 + k], w2[k * 128 + n], acc);
    h2[m * 128 + n] = fmaxf(acc + b2[n], 0.f);
}

__global__ void mlp3_kernel(const float* __restrict__ h2, const float* __restrict__ w3,
                            const float* __restrict__ b3, float* __restrict__ out) {
    int t = threadIdx.x;
    if (t >= 640) return;
    int m = t / 10, n = t % 10;
    float acc = 0.f;
#pragma unroll
    for (int k = 0; k < 128; ++k) acc = fmaf(h2[m * 128 + k], w3[k * 10 + n], acc);
    out[t] = fmaxf(acc + b3[n], 0.f);
}

// ---------------- launcher ----------------
extern "C" void kernel_launch(void* const* d_in, const int* in_sizes, int n_in,
                              void* d_out, int out_size, void* d_ws, size_t ws_size,
                              hipStream_t stream) {
    const float* x   = (const float*)d_in[0];
    const float* wih = (const float*)d_in[1];
    const float* whh = (const float*)d_in[2];
    const float* bih = (const float*)d_in[3];
    const float* bhh = (const float*)d_in[4];
    const float* qw[5] = {(const float*)d_in[5], (const float*)d_in[7], (const float*)d_in[9],
                          (const float*)d_in[11], (const float*)d_in[13]};
    const float* qb[5] = {(const float*)d_in[6], (const float*)d_in[8], (const float*)d_in[10],
                          (const float*)d_in[12], (const float*)d_in[14]};
    const float* w1 = (const float*)d_in[15];
    const float* b1 = (const float*)d_in[16];
    const float* w2 = (const float*)d_in[17];
    const float* b2 = (const float*)d_in[18];
    const float* w3 = (const float*)d_in[19];
    const float* b3 = (const float*)d_in[20];
    float* out = (float*)d_out;

    // ---- ws carve ----
    char* ws = (char*)d_ws;
    size_t off = 0;
    auto carve = [&](size_t sz) {
        char* q = ws + off;
        off += (sz + 255) & ~size_t(255);
        return q;
    };
    float* h4    = (float*)carve((size_t)Mm * 4 * 4);              // RNN out
    float* h16   = (float*)carve((size_t)Mm * 16 * 4);             // L0 out (fp32)
    float* zf32  = (float*)carve((size_t)Mm * 64 * 4);             // L0/L1 zf buffer
    short* p32   = (short*)carve((size_t)(Mm + 128) * 32 * 2);     // L1 out plane
    short* p64   = (short*)carve((size_t)(Mm + 128) * 64 * 2);     // L2 out plane
    short* p128  = (short*)carve((size_t)(Mm + 128) * 128 * 2);    // L3 out plane
    float* pooled = (float*)carve((size_t)Bb * Ss * 4);
    float* parts  = (float*)carve(12ull * 64 * 1024 * 4);
    float* h1m    = (float*)carve(64ull * 1024 * 4);
    float* h2m    = (float*)carve(64ull * 128 * 4);
    short* wh2 = (short*)carve(4096 * 2);
    short* wl2 = (short*)carve(4096 * 2);
    short* wh3 = (short*)carve(16384 * 2);
    short* wl3 = (short*)carve(16384 * 2);
    short* wh4 = (short*)carve(65536 * 2);
    short* wl4 = (short*)carve(65536 * 2);
    (void)ws_size;

    // ---- weight prep (frag-packed bf16 hi/lo) ----
    prep_wfrag<<<8,  256, 0, stream>>>(qw[2], wh2, wl2, 32, 128);
    prep_wfrag<<<16, 256, 0, stream>>>(qw[3], wh3, wl3, 64, 256);
    prep_wfrag<<<64, 256, 0, stream>>>(qw[4], wh4, wl4, 128, 512);

    // ---- RNN ----
    rnn_kernel2<<<Bb, 64, 0, stream>>>(x, wih, whh, bih, bhh, h4);

    // ---- layer0 (K=4, H=16): fp32 gemm + scan -> h16 ----
    {
        dim3 grid(Mm / 64, 1);
        qrnn_gemm<4><<<grid, 256, 0, stream>>>(h4, qw[0], qb[0], zf32, 32, 32, 16, 0, 16);
        int total = Bb * NCH * 16;
        scan_f2c<<<(total + 255) / 256, 256, 0, stream>>>(zf32, h16, 16, 32, 16, 0);
    }
    // ---- layer1 (K=16, H=32): fp32 gemm + scan -> bf16 plane p32 ----
    {
        dim3 grid(Mm / 64, 1);
        qrnn_gemm<16><<<grid, 256, 0, stream>>>(h16, qw[1], qb[1], zf32, 64, 64, 32, 0, 32);
        int total = Bb * NCH * 32;
        scan_f2p<<<(total + 255) / 256, 256, 0, stream>>>(zf32, p32, 32, 64, 32, 0);
    }
    // ---- fused layers 2..4 ----
    qrnn_fused_l2<<<Bb * 12, 512, 0, stream>>>(p32, wh2, wl2, qb[2], p64);
    qrnn_fused_l3<<<Bb * 12, 512, 0, stream>>>(p64, wh3, wl3, qb[3], p128);
    qrnn_fused_l4<<<Bb * 4, 512, 0, stream>>>(p128, wh4, wl4, qb[4], pooled);

    // ---- MLP ----
    mlp1_kernel<<<dim3(16, 12), 256, 0, stream>>>(pooled, w1, parts);
    mlp1_reduce<<<256, 256, 0, stream>>>(parts, b1, h1m);
    mlp2_kernel<<<64, 128, 0, stream>>>(h1m, w2, b2, h2m);
    mlp3_kernel<<<1, 640, 0, stream>>>(h2m, w3, b3, out);
    (void)in_sizes; (void)n_in; (void)out_size;
}